// Round 14
// baseline (232.311 us; speedup 1.0000x reference)
//
#include <hip/hip_runtime.h>
#include <hip/hip_bf16.h>

#define N 8192
#define THREADS 256
#define KCHUNKS 8
#define KCHUNK (N / KCHUNKS)   // 1024
#define BK 256
#define YSTR 264               // padded LDS stride (bf16 elements)
#define PSTR 264               // padded LDS stride (floats)

typedef __attribute__((ext_vector_type(8))) short short8;
typedef __attribute__((ext_vector_type(4))) float floatx4;

// ---- workspace byte offsets (total ~11.6 MB) ----
#define POST_OFF  0u           // float[4*N]: x,y,z,r2 rows     131072
#define Y1T_OFF   131072u      // bf16[32*N]                    524288
#define Y2T_OFF   655360u      // bf16[8*N]                     131072
#define P1_OFF    786432u      // float[8*N*32]                8388608
#define PC_OFF    9175040u     // float[8*N]                    262144
#define P2_OFF    9437184u     // float[8*N*8]                 2097152
#define CNTT_OFF  11534336u    // float[N]                       32768
#define CTR_OFF   11567104u    // int[128]: ctr1[64], ctr2[64]     512

__device__ __forceinline__ float bf2f(__hip_bfloat16 x) { return __bfloat162float(x); }

// mask from r2-form: s = r_k^2 - 2*dot(p_m,p_k);  s < 6.25 - r_m^2  <=>  d^2 < 6.25
#define MKA(PX,PY,PZ,RR,DST,IDX,PRX,PRY,PRZ,THR) { \
    const float dot = fmaf((PZ), (PRZ), fmaf((PY), (PRY), (PX) * (PRX))); \
    const float sv  = fmaf(dot, -2.0f, (RR)); \
    DST[IDX] = (sv < (THR)) ? (short)0x3F80 : (short)0; }

#define MKA8(AF, XA,XB,YA,YB,ZA,ZB,RA,RB, PRX,PRY,PRZ,THR) \
    MKA(XA.x, YA.x, ZA.x, RA.x, AF, 0, PRX, PRY, PRZ, THR) \
    MKA(XA.y, YA.y, ZA.y, RA.y, AF, 1, PRX, PRY, PRZ, THR) \
    MKA(XA.z, YA.z, ZA.z, RA.z, AF, 2, PRX, PRY, PRZ, THR) \
    MKA(XA.w, YA.w, ZA.w, RA.w, AF, 3, PRX, PRY, PRZ, THR) \
    MKA(XB.x, YB.x, ZB.x, RB.x, AF, 4, PRX, PRY, PRZ, THR) \
    MKA(XB.y, YB.y, ZB.y, RB.y, AF, 5, PRX, PRY, PRZ, THR) \
    MKA(XB.z, YB.z, ZB.z, RB.z, AF, 6, PRX, PRY, PRZ, THR) \
    MKA(XB.w, YB.w, ZB.w, RB.w, AF, 7, PRX, PRY, PRZ, THR)

// ---------------- prep: posT(x,y,z,r2) + y1 = x@W1+b1 -> y1T bf16 [32][N]; zero counters ----------------
__global__ __launch_bounds__(256) void k_prep(
    const float* __restrict__ lpf,    // (N,4) float32
    const float* __restrict__ Bm,     // (3,16)
    const float* __restrict__ emb,    // (13,8)
    const float* __restrict__ W1,     // (40,32)
    const float* __restrict__ b1,     // (32,)
    char* __restrict__ ws)
{
    __shared__ float sB[48], sEmb[104], sW1[1280], sb1[32];
    __shared__ __hip_bfloat16 sT[32 * YSTR];
    const int tid = threadIdx.x;

    if (blockIdx.x == 0 && tid < 128)
        ((int*)(ws + CTR_OFF))[tid] = 0;

    for (int i = tid; i < 48;   i += THREADS) sB[i]   = Bm[i];
    for (int i = tid; i < 104;  i += THREADS) sEmb[i] = emb[i];
    for (int i = tid; i < 1280; i += THREADS) sW1[i]  = W1[i];
    for (int i = tid; i < 32;   i += THREADS) sb1[i]  = b1[i];
    __syncthreads();

    const int row = blockIdx.x * THREADS + tid;
    const float4 lp = ((const float4*)lpf)[row];
    const float px = lp.x, py = lp.y, pz = lp.z;
    int fi = (int)lp.w;
    fi = fi < 0 ? 0 : (fi > 12 ? 12 : fi);
    const float r2 = px * px + py * py + pz * pz;
    float* posT = (float*)(ws + POST_OFF);
    posT[row] = px; posT[N + row] = py; posT[2 * N + row] = pz; posT[3 * N + row] = r2;

    const float TWO_PI = 6.283185307179586f;
    float xf[40];
    #pragma unroll
    for (int k = 0; k < 16; ++k) {
        const float pr = (px * sB[k] + py * sB[16 + k] + pz * sB[32 + k]) * TWO_PI;
        xf[k]      = sinf(pr);
        xf[16 + k] = cosf(pr);
    }
    #pragma unroll
    for (int m = 0; m < 8; ++m) xf[32 + m] = sEmb[fi * 8 + m];

    float acc[32];
    #pragma unroll
    for (int c = 0; c < 32; ++c) acc[c] = sb1[c];
    #pragma unroll
    for (int f = 0; f < 40; ++f) {
        const float xv = xf[f];
        #pragma unroll
        for (int c = 0; c < 32; ++c) acc[c] += xv * sW1[f * 32 + c];
    }
    #pragma unroll
    for (int c = 0; c < 32; ++c)
        sT[c * YSTR + tid] = __float2bfloat16(acc[c]);
    __syncthreads();
    __hip_bfloat16* y1t = (__hip_bfloat16*)(ws + Y1T_OFF);
    const int kb = blockIdx.x * THREADS;
    const int c32 = tid & 31, r8 = tid >> 5;
    #pragma unroll
    for (int rr = 0; rr < 4; ++rr) {
        const int r = r8 + rr * 8;
        *(uint4*)(y1t + (size_t)r * N + kb + c32 * 8) = *(const uint4*)&sT[r * YSTR + c32 * 8];
    }
}

// ---------------- agg1 + last-block mlp2 fixup ----------------
__global__ __launch_bounds__(256) void k_agg1(
    const float* __restrict__ W2,    // (32,8)
    const float* __restrict__ b2,    // (8,)
    char* __restrict__ ws)
{
    __shared__ __hip_bfloat16 sY[32 * YSTR];
    __shared__ float sPos[4 * PSTR];
    __shared__ float sW2f[256], sb2f[8];
    __shared__ int sdone;

    const float* posT = (const float*)(ws + POST_OFF);
    const __hip_bfloat16* y1t = (const __hip_bfloat16*)(ws + Y1T_OFF);
    float* part1 = (float*)(ws + P1_OFF);
    float* pcnt  = (float*)(ws + PC_OFF);

    const int tid  = threadIdx.x;
    const int lane = tid & 63;
    const int wv   = tid >> 6;
    const int quad = lane >> 4;
    const int ncol = lane & 15;
    const int bx = blockIdx.x, by = blockIdx.y;
    const int rowbase = bx * 128;
    const int kcbase  = by * KCHUNK;

    const int m0 = rowbase + wv * 32 + ncol;
    const int m1 = m0 + 16;
    const float prx0 = posT[m0], pry0 = posT[N + m0], prz0 = posT[2 * N + m0];
    const float thr0 = 6.25f - posT[3 * N + m0];
    const float prx1 = posT[m1], pry1 = posT[N + m1], prz1 = posT[2 * N + m1];
    const float thr1 = 6.25f - posT[3 * N + m1];

    short8 bones;
    #pragma unroll
    for (int j = 0; j < 8; ++j) bones[j] = (ncol == 0) ? (short)0x3F80 : (short)0;

    floatx4 acc[2][2], accc[2];
    #pragma unroll
    for (int t = 0; t < 2; ++t) {
        acc[t][0] = (floatx4){0.f,0.f,0.f,0.f};
        acc[t][1] = (floatx4){0.f,0.f,0.f,0.f};
        accc[t]   = (floatx4){0.f,0.f,0.f,0.f};
    }

    const int c32 = tid & 31, r8 = tid >> 5;
    for (int kb = 0; kb < KCHUNK; kb += BK) {
        const int kg = kcbase + kb;
        __syncthreads();
        #pragma unroll
        for (int rr = 0; rr < 4; ++rr) {
            const int r = r8 + rr * 8;
            *(uint4*)&sY[r * YSTR + c32 * 8] = *(const uint4*)(y1t + (size_t)r * N + kg + c32 * 8);
        }
        {
            const int dim = tid >> 6, i = tid & 63;
            *(float4*)&sPos[dim * PSTR + i * 4] = *(const float4*)(posT + (size_t)dim * N + kg + i * 4);
        }
        __syncthreads();

        #pragma unroll 2
        for (int kt = 0; kt < BK; kt += 32) {
            const int koff = kt + quad * 8;
            const float4 xa = *(const float4*)&sPos[koff],            xb = *(const float4*)&sPos[koff + 4];
            const float4 ya = *(const float4*)&sPos[PSTR + koff],     yb = *(const float4*)&sPos[PSTR + koff + 4];
            const float4 za = *(const float4*)&sPos[2 * PSTR + koff], zb = *(const float4*)&sPos[2 * PSTR + koff + 4];
            const float4 ra = *(const float4*)&sPos[3 * PSTR + koff], rb = *(const float4*)&sPos[3 * PSTR + koff + 4];

            short8 af0, af1;
            MKA8(af0, xa, xb, ya, yb, za, zb, ra, rb, prx0, pry0, prz0, thr0)
            MKA8(af1, xa, xb, ya, yb, za, zb, ra, rb, prx1, pry1, prz1, thr1)

            const short8 b0v = *(const short8*)&sY[(ncol)      * YSTR + koff];
            const short8 b1v = *(const short8*)&sY[(16 + ncol) * YSTR + koff];

            acc[0][0] = __builtin_amdgcn_mfma_f32_16x16x32_bf16(af0, b0v, acc[0][0], 0, 0, 0);
            acc[0][1] = __builtin_amdgcn_mfma_f32_16x16x32_bf16(af0, b1v, acc[0][1], 0, 0, 0);
            accc[0]   = __builtin_amdgcn_mfma_f32_16x16x32_bf16(af0, bones, accc[0], 0, 0, 0);
            acc[1][0] = __builtin_amdgcn_mfma_f32_16x16x32_bf16(af1, b0v, acc[1][0], 0, 0, 0);
            acc[1][1] = __builtin_amdgcn_mfma_f32_16x16x32_bf16(af1, b1v, acc[1][1], 0, 0, 0);
            accc[1]   = __builtin_amdgcn_mfma_f32_16x16x32_bf16(af1, bones, accc[1], 0, 0, 0);
        }
    }

    // write deterministic partials
    float* p1 = part1 + (size_t)by * N * 32;
    float* pc = pcnt  + (size_t)by * N;
    #pragma unroll
    for (int t = 0; t < 2; ++t) {
        const int orow0 = rowbase + wv * 32 + t * 16 + quad * 4;
        #pragma unroll
        for (int r = 0; r < 4; ++r) {
            const int orow = orow0 + r;
            p1[(size_t)orow * 32 + ncol]      = acc[t][0][r];
            p1[(size_t)orow * 32 + 16 + ncol] = acc[t][1][r];
            if (ncol == 0) pc[orow] = accc[t][r];
        }
    }

    // last-arriver does mlp2 for this bx's 128 rows
    __threadfence();
    if (tid == 0) sdone = atomicAdd((int*)(ws + CTR_OFF) + bx, 1);
    __syncthreads();
    if (sdone == KCHUNKS - 1) {
        __threadfence();
        for (int i = tid; i < 256; i += THREADS) sW2f[i] = W2[i];
        if (tid < 8) sb2f[tid] = b2[tid];
        __syncthreads();
        if (tid < 128) {
            const int row = rowbase + tid;
            const float* p1r = (const float*)(ws + P1_OFF);
            const float* pcr = (const float*)(ws + PC_OFF);
            float s[32];
            #pragma unroll
            for (int c = 0; c < 32; ++c) s[c] = 0.0f;
            float cv = 0.0f;
            for (int kc = 0; kc < KCHUNKS; ++kc) {
                const float4* p4 = (const float4*)(p1r + ((size_t)kc * N + row) * 32);
                #pragma unroll
                for (int k = 0; k < 8; ++k) {
                    const float4 v = p4[k];
                    s[4*k+0] += v.x; s[4*k+1] += v.y; s[4*k+2] += v.z; s[4*k+3] += v.w;
                }
                cv += pcr[(size_t)kc * N + row];
            }
            const float inv = 1.0f / (cv + 1e-6f);
            ((float*)(ws + CNTT_OFF))[row] = cv;

            float o[8];
            #pragma unroll
            for (int j = 0; j < 8; ++j) o[j] = sb2f[j];
            #pragma unroll
            for (int c = 0; c < 32; ++c) {
                const float hv = fmaxf(s[c] * inv, 0.0f);
                #pragma unroll
                for (int j = 0; j < 8; ++j) o[j] += hv * sW2f[c * 8 + j];
            }
            __hip_bfloat16* y2t = (__hip_bfloat16*)(ws + Y2T_OFF);
            #pragma unroll
            for (int j = 0; j < 8; ++j)
                y2t[(size_t)j * N + row] = __float2bfloat16(o[j]);
        }
    }
}

// ---------------- agg2 + last-block out fixup ----------------
__global__ __launch_bounds__(256) void k_agg2(char* __restrict__ ws, float* __restrict__ out)
{
    __shared__ __hip_bfloat16 sY[9 * YSTR];   // rows 0-7 data, row 8 zeros
    __shared__ float sPos[4 * PSTR];
    __shared__ int sdone;

    const float* posT = (const float*)(ws + POST_OFF);
    const __hip_bfloat16* y2t = (const __hip_bfloat16*)(ws + Y2T_OFF);
    float* part2 = (float*)(ws + P2_OFF);

    const int tid  = threadIdx.x;
    const int lane = tid & 63;
    const int wv   = tid >> 6;
    const int quad = lane >> 4;
    const int ncol = lane & 15;
    const int bx = blockIdx.x, by = blockIdx.y;
    const int rowbase = bx * 128;
    const int kcbase  = by * KCHUNK;

    if (tid < 32) {
        const uint4 z = {0u, 0u, 0u, 0u};
        *(uint4*)&sY[8 * YSTR + tid * 8] = z;
    }

    const int m0 = rowbase + wv * 32 + ncol;
    const int m1 = m0 + 16;
    const float prx0 = posT[m0], pry0 = posT[N + m0], prz0 = posT[2 * N + m0];
    const float thr0 = 6.25f - posT[3 * N + m0];
    const float prx1 = posT[m1], pry1 = posT[N + m1], prz1 = posT[2 * N + m1];
    const float thr1 = 6.25f - posT[3 * N + m1];

    const int brow = (ncol < 8) ? ncol : 8;

    floatx4 acc2a[2];
    acc2a[0] = (floatx4){0.f,0.f,0.f,0.f};
    acc2a[1] = (floatx4){0.f,0.f,0.f,0.f};

    const int c32 = tid & 31, r8 = tid >> 5;
    for (int kb = 0; kb < KCHUNK; kb += BK) {
        const int kg = kcbase + kb;
        __syncthreads();
        *(uint4*)&sY[r8 * YSTR + c32 * 8] = *(const uint4*)(y2t + (size_t)r8 * N + kg + c32 * 8);
        {
            const int dim = tid >> 6, i = tid & 63;
            *(float4*)&sPos[dim * PSTR + i * 4] = *(const float4*)(posT + (size_t)dim * N + kg + i * 4);
        }
        __syncthreads();

        #pragma unroll 2
        for (int kt = 0; kt < BK; kt += 32) {
            const int koff = kt + quad * 8;
            const float4 xa = *(const float4*)&sPos[koff],            xb = *(const float4*)&sPos[koff + 4];
            const float4 ya = *(const float4*)&sPos[PSTR + koff],     yb = *(const float4*)&sPos[PSTR + koff + 4];
            const float4 za = *(const float4*)&sPos[2 * PSTR + koff], zb = *(const float4*)&sPos[2 * PSTR + koff + 4];
            const float4 ra = *(const float4*)&sPos[3 * PSTR + koff], rb = *(const float4*)&sPos[3 * PSTR + koff + 4];

            short8 af0, af1;
            MKA8(af0, xa, xb, ya, yb, za, zb, ra, rb, prx0, pry0, prz0, thr0)
            MKA8(af1, xa, xb, ya, yb, za, zb, ra, rb, prx1, pry1, prz1, thr1)

            const short8 b0v = *(const short8*)&sY[brow * YSTR + koff];
            acc2a[0] = __builtin_amdgcn_mfma_f32_16x16x32_bf16(af0, b0v, acc2a[0], 0, 0, 0);
            acc2a[1] = __builtin_amdgcn_mfma_f32_16x16x32_bf16(af1, b0v, acc2a[1], 0, 0, 0);
        }
    }

    float* p2 = part2 + (size_t)by * N * 8;
    #pragma unroll
    for (int t = 0; t < 2; ++t) {
        const int orow0 = rowbase + wv * 32 + t * 16 + quad * 4;
        #pragma unroll
        for (int r = 0; r < 4; ++r) {
            if (ncol < 8) {
                const int orow = orow0 + r;
                p2[(size_t)orow * 8 + ncol] = acc2a[t][r];
            }
        }
    }

    // last-arriver writes final output for this bx's 128 rows
    __threadfence();
    if (tid == 0) sdone = atomicAdd((int*)(ws + CTR_OFF) + 64 + bx, 1);
    __syncthreads();
    if (sdone == KCHUNKS - 1) {
        __threadfence();
        if (tid < 128) {
            const int row = rowbase + tid;
            const float* p2r = (const float*)(ws + P2_OFF);
            const float  cv  = ((const float*)(ws + CNTT_OFF))[row];
            const float  inv = 1.0f / (cv + 1e-6f);
            float s[8];
            #pragma unroll
            for (int c = 0; c < 8; ++c) s[c] = 0.0f;
            for (int kc = 0; kc < KCHUNKS; ++kc) {
                const float4* p4 = (const float4*)(p2r + ((size_t)kc * N + row) * 8);
                const float4 v0 = p4[0], v1 = p4[1];
                s[0] += v0.x; s[1] += v0.y; s[2] += v0.z; s[3] += v0.w;
                s[4] += v1.x; s[5] += v1.y; s[6] += v1.z; s[7] += v1.w;
            }
            float4* op = (float4*)(out + (size_t)row * 8);
            op[0] = make_float4(fmaxf(s[0] * inv, 0.0f), fmaxf(s[1] * inv, 0.0f),
                                fmaxf(s[2] * inv, 0.0f), fmaxf(s[3] * inv, 0.0f));
            op[1] = make_float4(fmaxf(s[4] * inv, 0.0f), fmaxf(s[5] * inv, 0.0f),
                                fmaxf(s[6] * inv, 0.0f), fmaxf(s[7] * inv, 0.0f));
        }
    }
}

extern "C" void kernel_launch(void* const* d_in, const int* in_sizes, int n_in,
                              void* d_out, int out_size, void* d_ws, size_t ws_size,
                              hipStream_t stream) {
    (void)in_sizes; (void)n_in; (void)out_size; (void)ws_size;
    char* ws = (char*)d_ws;
    const float* lpf = (const float*)d_in[0];
    const float* B   = (const float*)d_in[1];
    const float* emb = (const float*)d_in[2];
    const float* W1  = (const float*)d_in[3];
    const float* b1  = (const float*)d_in[4];
    const float* W2  = (const float*)d_in[5];
    const float* b2  = (const float*)d_in[6];

    k_prep<<<N / THREADS, THREADS, 0, stream>>>(lpf, B, emb, W1, b1, ws);
    k_agg1<<<dim3(N / 128, KCHUNKS), THREADS, 0, stream>>>(W2, b2, ws);
    k_agg2<<<dim3(N / 128, KCHUNKS), THREADS, 0, stream>>>(ws, (float*)d_out);
}

// Round 15
// 127.116 us; speedup vs baseline: 1.8275x; 1.8275x over previous
//
#include <hip/hip_runtime.h>
#include <hip/hip_bf16.h>

#define N 8192
#define THREADS 256
#define KCHUNKS 8
#define KCHUNK (N / KCHUNKS)   // 1024
#define BK 256
#define YSTR 264               // padded LDS stride (bf16 elements)
#define PSTR 264               // padded LDS stride (floats) for pos rows

typedef __attribute__((ext_vector_type(8))) short short8;
typedef __attribute__((ext_vector_type(4))) float floatx4;

// ---- workspace byte offsets (total ~11.6 MB) ----
#define POST_OFF  0u           // float[4*N]: x,y,z,r2 rows     131072
#define Y1T_OFF   131072u      // bf16[32*N]                    524288
#define Y2T_OFF   655360u      // bf16[8*N]                     131072
#define P1_OFF    786432u      // float[8*N*32]                8388608
#define PC_OFF    9175040u     // float[8*N]                    262144
#define P2_OFF    9437184u     // float[8*N*8]                 2097152
#define CNTT_OFF  11534336u    // float[N]                       32768

__device__ __forceinline__ float bf2f(__hip_bfloat16 x) { return __bfloat162float(x); }

// ---------------- prep: posT(x,y,z,r2) + y1 = x@W1+b1 -> y1T bf16 [32][N] ----------------
__global__ __launch_bounds__(256) void k_prep(
    const float* __restrict__ lpf,    // (N,4) float32
    const float* __restrict__ Bm,     // (3,16)
    const float* __restrict__ emb,    // (13,8)
    const float* __restrict__ W1,     // (40,32)
    const float* __restrict__ b1,     // (32,)
    char* __restrict__ ws)
{
    __shared__ float sB[48], sEmb[104], sW1[1280], sb1[32];
    __shared__ __hip_bfloat16 sT[32 * YSTR];
    const int tid = threadIdx.x;
    for (int i = tid; i < 48;   i += THREADS) sB[i]   = Bm[i];
    for (int i = tid; i < 104;  i += THREADS) sEmb[i] = emb[i];
    for (int i = tid; i < 1280; i += THREADS) sW1[i]  = W1[i];
    for (int i = tid; i < 32;   i += THREADS) sb1[i]  = b1[i];
    __syncthreads();

    const int row = blockIdx.x * THREADS + tid;
    const float4 lp = ((const float4*)lpf)[row];
    const float px = lp.x, py = lp.y, pz = lp.z;
    int fi = (int)lp.w;
    fi = fi < 0 ? 0 : (fi > 12 ? 12 : fi);
    const float r2 = px * px + py * py + pz * pz;
    float* posT = (float*)(ws + POST_OFF);
    posT[row] = px; posT[N + row] = py; posT[2 * N + row] = pz; posT[3 * N + row] = r2;

    const float TWO_PI = 6.283185307179586f;
    float xf[40];
    #pragma unroll
    for (int k = 0; k < 16; ++k) {
        const float pr = (px * sB[k] + py * sB[16 + k] + pz * sB[32 + k]) * TWO_PI;
        xf[k]      = sinf(pr);
        xf[16 + k] = cosf(pr);
    }
    #pragma unroll
    for (int m = 0; m < 8; ++m) xf[32 + m] = sEmb[fi * 8 + m];

    float acc[32];
    #pragma unroll
    for (int c = 0; c < 32; ++c) acc[c] = sb1[c];
    #pragma unroll
    for (int f = 0; f < 40; ++f) {
        const float xv = xf[f];
        #pragma unroll
        for (int c = 0; c < 32; ++c) acc[c] += xv * sW1[f * 32 + c];
    }
    // transpose tile: row c = feature, col = tid (single bf16)
    #pragma unroll
    for (int c = 0; c < 32; ++c)
        sT[c * YSTR + tid] = __float2bfloat16(acc[c]);
    __syncthreads();
    __hip_bfloat16* y1t = (__hip_bfloat16*)(ws + Y1T_OFF);
    const int kb = blockIdx.x * THREADS;
    const int c32 = tid & 31, r8 = tid >> 5;
    #pragma unroll
    for (int rr = 0; rr < 4; ++rr) {
        const int r = r8 + rr * 8;
        *(uint4*)(y1t + (size_t)r * N + kb + c32 * 8) = *(const uint4*)&sT[r * YSTR + c32 * 8];
    }
}

// mask from r2-form: s = r_k^2 - 2*dot(p_m,p_k);  s < 6.25 - r_m^2  <=>  d^2 < 6.25
#define MKA(PX,PY,PZ,RR,DST,IDX,PRX,PRY,PRZ,THR) { \
    const float dot = fmaf((PZ), (PRZ), fmaf((PY), (PRY), (PX) * (PRX))); \
    const float sv  = fmaf(dot, -2.0f, (RR)); \
    DST[IDX] = (sv < (THR)) ? (short)0x3F80 : (short)0; }

#define MKA8(AF, XA,XB,YA,YB,ZA,ZB,RA,RB, PRX,PRY,PRZ,THR) \
    MKA(XA.x, YA.x, ZA.x, RA.x, AF, 0, PRX, PRY, PRZ, THR) \
    MKA(XA.y, YA.y, ZA.y, RA.y, AF, 1, PRX, PRY, PRZ, THR) \
    MKA(XA.z, YA.z, ZA.z, RA.z, AF, 2, PRX, PRY, PRZ, THR) \
    MKA(XA.w, YA.w, ZA.w, RA.w, AF, 3, PRX, PRY, PRZ, THR) \
    MKA(XB.x, YB.x, ZB.x, RB.x, AF, 4, PRX, PRY, PRZ, THR) \
    MKA(XB.y, YB.y, ZB.y, RB.y, AF, 5, PRX, PRY, PRZ, THR) \
    MKA(XB.z, YB.z, ZB.z, RB.z, AF, 6, PRX, PRY, PRZ, THR) \
    MKA(XB.w, YB.w, ZB.w, RB.w, AF, 7, PRX, PRY, PRZ, THR)

// ---------------- agg1: partial sums(A @ y1) + cnt via MFMA, 128-row blocks ----------------
__global__ __launch_bounds__(256) void k_agg1(char* __restrict__ ws)
{
    __shared__ __hip_bfloat16 sY[32 * YSTR];
    __shared__ float sPos[4 * PSTR];

    const float* posT = (const float*)(ws + POST_OFF);
    const __hip_bfloat16* y1t = (const __hip_bfloat16*)(ws + Y1T_OFF);
    float* part1 = (float*)(ws + P1_OFF);
    float* pcnt  = (float*)(ws + PC_OFF);

    const int tid  = threadIdx.x;
    const int lane = tid & 63;
    const int wv   = tid >> 6;        // wave 0..3
    const int quad = lane >> 4;       // 0..3
    const int ncol = lane & 15;
    const int rowbase = blockIdx.x * 128;
    const int kcbase  = blockIdx.y * KCHUNK;

    // two A-side row tiles per wave
    const int m0 = rowbase + wv * 32 + ncol;
    const int m1 = m0 + 16;
    const float prx0 = posT[m0], pry0 = posT[N + m0], prz0 = posT[2 * N + m0];
    const float thr0 = 6.25f - posT[3 * N + m0];
    const float prx1 = posT[m1], pry1 = posT[N + m1], prz1 = posT[2 * N + m1];
    const float thr1 = 6.25f - posT[3 * N + m1];

    short8 bones;
    #pragma unroll
    for (int j = 0; j < 8; ++j) bones[j] = (ncol == 0) ? (short)0x3F80 : (short)0;

    floatx4 acc[2][2], accc[2];
    #pragma unroll
    for (int t = 0; t < 2; ++t) {
        acc[t][0] = (floatx4){0.f,0.f,0.f,0.f};
        acc[t][1] = (floatx4){0.f,0.f,0.f,0.f};
        accc[t]   = (floatx4){0.f,0.f,0.f,0.f};
    }

    const int c32 = tid & 31, r8 = tid >> 5;
    for (int kb = 0; kb < KCHUNK; kb += BK) {
        const int kg = kcbase + kb;
        __syncthreads();
        #pragma unroll
        for (int rr = 0; rr < 4; ++rr) {
            const int r = r8 + rr * 8;
            *(uint4*)&sY[r * YSTR + c32 * 8] = *(const uint4*)(y1t + (size_t)r * N + kg + c32 * 8);
        }
        {   // stage pos rows x,y,z,r2: 4 x 256 floats, 1 float4/thread
            const int dim = tid >> 6, i = tid & 63;
            *(float4*)&sPos[dim * PSTR + i * 4] = *(const float4*)(posT + (size_t)dim * N + kg + i * 4);
        }
        __syncthreads();

        #pragma unroll 2
        for (int kt = 0; kt < BK; kt += 32) {
            const int koff = kt + quad * 8;
            const float4 xa = *(const float4*)&sPos[koff],            xb = *(const float4*)&sPos[koff + 4];
            const float4 ya = *(const float4*)&sPos[PSTR + koff],     yb = *(const float4*)&sPos[PSTR + koff + 4];
            const float4 za = *(const float4*)&sPos[2 * PSTR + koff], zb = *(const float4*)&sPos[2 * PSTR + koff + 4];
            const float4 ra = *(const float4*)&sPos[3 * PSTR + koff], rb = *(const float4*)&sPos[3 * PSTR + koff + 4];

            short8 af0, af1;
            MKA8(af0, xa, xb, ya, yb, za, zb, ra, rb, prx0, pry0, prz0, thr0)
            MKA8(af1, xa, xb, ya, yb, za, zb, ra, rb, prx1, pry1, prz1, thr1)

            const short8 b0 = *(const short8*)&sY[(ncol)      * YSTR + koff];
            const short8 b1 = *(const short8*)&sY[(16 + ncol) * YSTR + koff];

            acc[0][0] = __builtin_amdgcn_mfma_f32_16x16x32_bf16(af0, b0, acc[0][0], 0, 0, 0);
            acc[0][1] = __builtin_amdgcn_mfma_f32_16x16x32_bf16(af0, b1, acc[0][1], 0, 0, 0);
            accc[0]   = __builtin_amdgcn_mfma_f32_16x16x32_bf16(af0, bones, accc[0], 0, 0, 0);
            acc[1][0] = __builtin_amdgcn_mfma_f32_16x16x32_bf16(af1, b0, acc[1][0], 0, 0, 0);
            acc[1][1] = __builtin_amdgcn_mfma_f32_16x16x32_bf16(af1, b1, acc[1][1], 0, 0, 0);
            accc[1]   = __builtin_amdgcn_mfma_f32_16x16x32_bf16(af1, bones, accc[1], 0, 0, 0);
        }
    }

    // C layout: col = ncol, row = quad*4 + r
    float* p1 = part1 + (size_t)blockIdx.y * N * 32;
    float* pc = pcnt  + (size_t)blockIdx.y * N;
    #pragma unroll
    for (int t = 0; t < 2; ++t) {
        const int orow0 = rowbase + wv * 32 + t * 16 + quad * 4;
        #pragma unroll
        for (int r = 0; r < 4; ++r) {
            const int orow = orow0 + r;
            p1[(size_t)orow * 32 + ncol]      = acc[t][0][r];
            p1[(size_t)orow * 32 + 16 + ncol] = acc[t][1][r];
            if (ncol == 0) pc[orow] = accc[t][r];
        }
    }
}

// ---------------- mlp2: h = relu(sum/(cnt+eps)); y2 = h@W2+b2 -> y2T bf16 [8][N]; cntT ----------------
__global__ __launch_bounds__(256) void k_mlp2(
    const float* __restrict__ W2,    // (32,8)
    const float* __restrict__ b2,    // (8,)
    char* __restrict__ ws)
{
    __shared__ float sW2[256], sb2[8];
    __shared__ __hip_bfloat16 sT[8 * YSTR];
    const int tid = threadIdx.x;
    for (int i = tid; i < 256; i += THREADS) sW2[i] = W2[i];
    if (tid < 8) sb2[tid] = b2[tid];
    __syncthreads();

    const int row = blockIdx.x * THREADS + tid;
    const float* part1 = (const float*)(ws + P1_OFF);
    const float* pcnt  = (const float*)(ws + PC_OFF);

    float s[32];
    #pragma unroll
    for (int c = 0; c < 32; ++c) s[c] = 0.0f;
    float cv = 0.0f;
    for (int kc = 0; kc < KCHUNKS; ++kc) {
        const float4* p4 = (const float4*)(part1 + ((size_t)kc * N + row) * 32);
        #pragma unroll
        for (int k = 0; k < 8; ++k) {
            const float4 v = p4[k];
            s[4*k+0] += v.x; s[4*k+1] += v.y; s[4*k+2] += v.z; s[4*k+3] += v.w;
        }
        cv += pcnt[(size_t)kc * N + row];
    }
    const float inv = 1.0f / (cv + 1e-6f);
    ((float*)(ws + CNTT_OFF))[row] = cv;

    float o[8];
    #pragma unroll
    for (int j = 0; j < 8; ++j) o[j] = sb2[j];
    #pragma unroll
    for (int c = 0; c < 32; ++c) {
        const float hv = fmaxf(s[c] * inv, 0.0f);
        #pragma unroll
        for (int j = 0; j < 8; ++j) o[j] += hv * sW2[c * 8 + j];
    }
    #pragma unroll
    for (int j = 0; j < 8; ++j)
        sT[j * YSTR + tid] = __float2bfloat16(o[j]);
    __syncthreads();
    __hip_bfloat16* y2t = (__hip_bfloat16*)(ws + Y2T_OFF);
    const int kb = blockIdx.x * THREADS;
    const int c32 = tid & 31, r8 = tid >> 5;
    *(uint4*)(y2t + (size_t)r8 * N + kb + c32 * 8) = *(const uint4*)&sT[r8 * YSTR + c32 * 8];
}

// ---------------- agg2: partial sums(A @ y2) via MFMA, 128-row blocks ----------------
__global__ __launch_bounds__(256) void k_agg2(char* __restrict__ ws)
{
    __shared__ __hip_bfloat16 sY[9 * YSTR];   // rows 0-7 data, row 8 zeros
    __shared__ float sPos[4 * PSTR];

    const float* posT = (const float*)(ws + POST_OFF);
    const __hip_bfloat16* y2t = (const __hip_bfloat16*)(ws + Y2T_OFF);
    float* part2 = (float*)(ws + P2_OFF);

    const int tid  = threadIdx.x;
    const int lane = tid & 63;
    const int wv   = tid >> 6;
    const int quad = lane >> 4;
    const int ncol = lane & 15;
    const int rowbase = blockIdx.x * 128;
    const int kcbase  = blockIdx.y * KCHUNK;

    // zero row 8 (read by lanes with ncol >= 8)
    if (tid < 32) {
        const uint4 z = {0u, 0u, 0u, 0u};
        *(uint4*)&sY[8 * YSTR + tid * 8] = z;
    }

    const int m0 = rowbase + wv * 32 + ncol;
    const int m1 = m0 + 16;
    const float prx0 = posT[m0], pry0 = posT[N + m0], prz0 = posT[2 * N + m0];
    const float thr0 = 6.25f - posT[3 * N + m0];
    const float prx1 = posT[m1], pry1 = posT[N + m1], prz1 = posT[2 * N + m1];
    const float thr1 = 6.25f - posT[3 * N + m1];

    const int brow = (ncol < 8) ? ncol : 8;

    floatx4 acc[2];
    acc[0] = (floatx4){0.f,0.f,0.f,0.f};
    acc[1] = (floatx4){0.f,0.f,0.f,0.f};

    const int c32 = tid & 31, r8 = tid >> 5;
    for (int kb = 0; kb < KCHUNK; kb += BK) {
        const int kg = kcbase + kb;
        __syncthreads();
        *(uint4*)&sY[r8 * YSTR + c32 * 8] = *(const uint4*)(y2t + (size_t)r8 * N + kg + c32 * 8);
        {
            const int dim = tid >> 6, i = tid & 63;
            *(float4*)&sPos[dim * PSTR + i * 4] = *(const float4*)(posT + (size_t)dim * N + kg + i * 4);
        }
        __syncthreads();

        #pragma unroll 2
        for (int kt = 0; kt < BK; kt += 32) {
            const int koff = kt + quad * 8;
            const float4 xa = *(const float4*)&sPos[koff],            xb = *(const float4*)&sPos[koff + 4];
            const float4 ya = *(const float4*)&sPos[PSTR + koff],     yb = *(const float4*)&sPos[PSTR + koff + 4];
            const float4 za = *(const float4*)&sPos[2 * PSTR + koff], zb = *(const float4*)&sPos[2 * PSTR + koff + 4];
            const float4 ra = *(const float4*)&sPos[3 * PSTR + koff], rb = *(const float4*)&sPos[3 * PSTR + koff + 4];

            short8 af0, af1;
            MKA8(af0, xa, xb, ya, yb, za, zb, ra, rb, prx0, pry0, prz0, thr0)
            MKA8(af1, xa, xb, ya, yb, za, zb, ra, rb, prx1, pry1, prz1, thr1)

            const short8 b0 = *(const short8*)&sY[brow * YSTR + koff];
            acc[0] = __builtin_amdgcn_mfma_f32_16x16x32_bf16(af0, b0, acc[0], 0, 0, 0);
            acc[1] = __builtin_amdgcn_mfma_f32_16x16x32_bf16(af1, b0, acc[1], 0, 0, 0);
        }
    }

    float* p2 = part2 + (size_t)blockIdx.y * N * 8;
    #pragma unroll
    for (int t = 0; t < 2; ++t) {
        const int orow0 = rowbase + wv * 32 + t * 16 + quad * 4;
        #pragma unroll
        for (int r = 0; r < 4; ++r) {
            if (ncol < 8) {
                const int orow = orow0 + r;
                p2[(size_t)orow * 8 + ncol] = acc[t][r];
            }
        }
    }
}

// ---------------- out = relu(sum/(cnt+eps)) -> float32 ----------------
__global__ __launch_bounds__(256) void k_out(char* __restrict__ ws, float* __restrict__ out)
{
    const int tid = threadIdx.x;
    const int row = blockIdx.x * THREADS + tid;
    const float* part2 = (const float*)(ws + P2_OFF);
    const float  cv  = ((const float*)(ws + CNTT_OFF))[row];
    const float  inv = 1.0f / (cv + 1e-6f);
    float s[8];
    #pragma unroll
    for (int c = 0; c < 8; ++c) s[c] = 0.0f;
    for (int kc = 0; kc < KCHUNKS; ++kc) {
        const float4* p4 = (const float4*)(part2 + ((size_t)kc * N + row) * 8);
        const float4 v0 = p4[0], v1 = p4[1];
        s[0] += v0.x; s[1] += v0.y; s[2] += v0.z; s[3] += v0.w;
        s[4] += v1.x; s[5] += v1.y; s[6] += v1.z; s[7] += v1.w;
    }
    float4* op = (float4*)(out + (size_t)row * 8);
    op[0] = make_float4(fmaxf(s[0] * inv, 0.0f), fmaxf(s[1] * inv, 0.0f),
                        fmaxf(s[2] * inv, 0.0f), fmaxf(s[3] * inv, 0.0f));
    op[1] = make_float4(fmaxf(s[4] * inv, 0.0f), fmaxf(s[5] * inv, 0.0f),
                        fmaxf(s[6] * inv, 0.0f), fmaxf(s[7] * inv, 0.0f));
}

extern "C" void kernel_launch(void* const* d_in, const int* in_sizes, int n_in,
                              void* d_out, int out_size, void* d_ws, size_t ws_size,
                              hipStream_t stream) {
    (void)in_sizes; (void)n_in; (void)out_size; (void)ws_size;
    char* ws = (char*)d_ws;
    const float* lpf = (const float*)d_in[0];
    const float* B   = (const float*)d_in[1];
    const float* emb = (const float*)d_in[2];
    const float* W1  = (const float*)d_in[3];
    const float* b1  = (const float*)d_in[4];
    const float* W2  = (const float*)d_in[5];
    const float* b2  = (const float*)d_in[6];

    k_prep<<<N / THREADS, THREADS, 0, stream>>>(lpf, B, emb, W1, b1, ws);
    k_agg1<<<dim3(N / 128, KCHUNKS), THREADS, 0, stream>>>(ws);
    k_mlp2<<<N / THREADS, THREADS, 0, stream>>>(W2, b2, ws);
    k_agg2<<<dim3(N / 128, KCHUNKS), THREADS, 0, stream>>>(ws);
    k_out <<<N / THREADS, THREADS, 0, stream>>>(ws, (float*)d_out);
}

// Round 16
// 121.329 us; speedup vs baseline: 1.9147x; 1.0477x over previous
//
#include <hip/hip_runtime.h>
#include <hip/hip_bf16.h>

#define N 8192
#define THREADS 256
#define KCHUNKS 8
#define KCHUNK (N / KCHUNKS)   // 1024
#define BK 256
#define YSTR 264               // padded LDS stride (bf16 elements)
#define PSTR 264               // padded LDS stride (floats) for pos rows

typedef __attribute__((ext_vector_type(8))) short short8;
typedef __attribute__((ext_vector_type(4))) float floatx4;

// ---- workspace byte offsets (total ~11.6 MB) ----
#define POST_OFF  0u           // float[4*N]: x,y,z,r2 rows     131072
#define Y1T_OFF   131072u      // bf16[32*N]                    524288
#define Y2T_OFF   655360u      // bf16[8*N]                     131072
#define P1_OFF    786432u      // float[8*N*32]                8388608
#define PC_OFF    9175040u     // float[8*N]                    262144
#define P2_OFF    9437184u     // float[8*N*8]                 2097152
#define CNTT_OFF  11534336u    // float[N]                       32768

__device__ __forceinline__ float bf2f(__hip_bfloat16 x) { return __bfloat162float(x); }

// ---------------- prep v2: 256 blocks x 32 rows, 8 threads/row ----------------
// posT(x,y,z,r2) + y1 = x@W1+b1 -> y1T bf16 [32][N]; bit-identical to v1 per-row math
__global__ __launch_bounds__(256) void k_prep(
    const float* __restrict__ lpf,    // (N,4) float32
    const float* __restrict__ Bm,     // (3,16)
    const float* __restrict__ emb,    // (13,8)
    const float* __restrict__ W1,     // (40,32)
    const float* __restrict__ b1,     // (32,)
    char* __restrict__ ws)
{
    __shared__ float sB[48], sEmb[104], sW1[1280], sb1[32];
    __shared__ float xfs[32][41];              // per-row feature vector
    __shared__ __hip_bfloat16 sT[32 * 36];     // [feat][row_local], stride 36

    const int tid = threadIdx.x;
    for (int i = tid; i < 48;   i += THREADS) sB[i]   = Bm[i];
    for (int i = tid; i < 104;  i += THREADS) sEmb[i] = emb[i];
    for (int i = tid; i < 1280; i += THREADS) sW1[i]  = W1[i];
    for (int i = tid; i < 32;   i += THREADS) sb1[i]  = b1[i];
    __syncthreads();

    const int row_local = tid >> 3;            // 0..31
    const int fslice    = tid & 7;             // 0..7
    const int base = blockIdx.x * 32;
    const int row  = base + row_local;

    const float4 lp = ((const float4*)lpf)[row];
    const float px = lp.x, py = lp.y, pz = lp.z;
    int fi = (int)lp.w;
    fi = fi < 0 ? 0 : (fi > 12 ? 12 : fi);
    const float r2 = px * px + py * py + pz * pz;
    float* posT = (float*)(ws + POST_OFF);
    if (fslice < 4) {
        const float v = (fslice == 0) ? px : (fslice == 1) ? py : (fslice == 2) ? pz : r2;
        posT[(size_t)fslice * N + row] = v;
    }

    const float TWO_PI = 6.283185307179586f;
    #pragma unroll
    for (int t = 0; t < 2; ++t) {
        const int k = fslice * 2 + t;          // 0..15
        const float pr = (px * sB[k] + py * sB[16 + k] + pz * sB[32 + k]) * TWO_PI;
        xfs[row_local][k]      = sinf(pr);
        xfs[row_local][16 + k] = cosf(pr);
    }
    xfs[row_local][32 + fslice] = sEmb[fi * 8 + fslice];
    __syncthreads();

    // each thread: 4 output features [fslice*4, fslice*4+4), accumulate over f = 0..39 (same order as v1)
    float acc[4];
    #pragma unroll
    for (int j = 0; j < 4; ++j) acc[j] = sb1[fslice * 4 + j];
    #pragma unroll
    for (int f = 0; f < 40; ++f) {
        const float xv = xfs[row_local][f];
        #pragma unroll
        for (int j = 0; j < 4; ++j)
            acc[j] += xv * sW1[f * 32 + fslice * 4 + j];
    }
    #pragma unroll
    for (int j = 0; j < 4; ++j)
        sT[(fslice * 4 + j) * 36 + row_local] = __float2bfloat16(acc[j]);
    __syncthreads();

    // write y1t[32][N] slice cols [base, base+32): 128 uint4s
    __hip_bfloat16* y1t = (__hip_bfloat16*)(ws + Y1T_OFF);
    if (tid < 128) {
        const int feat = tid >> 2, chunk = tid & 3;
        *(uint4*)(y1t + (size_t)feat * N + base + chunk * 8) = *(const uint4*)&sT[feat * 36 + chunk * 8];
    }
}

// mask from r2-form: s = r_k^2 - 2*dot(p_m,p_k);  s < 6.25 - r_m^2  <=>  d^2 < 6.25
#define MKA(PX,PY,PZ,RR,DST,IDX,PRX,PRY,PRZ,THR) { \
    const float dot = fmaf((PZ), (PRZ), fmaf((PY), (PRY), (PX) * (PRX))); \
    const float sv  = fmaf(dot, -2.0f, (RR)); \
    DST[IDX] = (sv < (THR)) ? (short)0x3F80 : (short)0; }

#define MKA8(AF, XA,XB,YA,YB,ZA,ZB,RA,RB, PRX,PRY,PRZ,THR) \
    MKA(XA.x, YA.x, ZA.x, RA.x, AF, 0, PRX, PRY, PRZ, THR) \
    MKA(XA.y, YA.y, ZA.y, RA.y, AF, 1, PRX, PRY, PRZ, THR) \
    MKA(XA.z, YA.z, ZA.z, RA.z, AF, 2, PRX, PRY, PRZ, THR) \
    MKA(XA.w, YA.w, ZA.w, RA.w, AF, 3, PRX, PRY, PRZ, THR) \
    MKA(XB.x, YB.x, ZB.x, RB.x, AF, 4, PRX, PRY, PRZ, THR) \
    MKA(XB.y, YB.y, ZB.y, RB.y, AF, 5, PRX, PRY, PRZ, THR) \
    MKA(XB.z, YB.z, ZB.z, RB.z, AF, 6, PRX, PRY, PRZ, THR) \
    MKA(XB.w, YB.w, ZB.w, RB.w, AF, 7, PRX, PRY, PRZ, THR)

// ---------------- agg1: partial sums(A @ y1) + cnt via MFMA, 128-row blocks ----------------
__global__ __launch_bounds__(256) void k_agg1(char* __restrict__ ws)
{
    __shared__ __hip_bfloat16 sY[32 * YSTR];
    __shared__ float sPos[4 * PSTR];

    const float* posT = (const float*)(ws + POST_OFF);
    const __hip_bfloat16* y1t = (const __hip_bfloat16*)(ws + Y1T_OFF);
    float* part1 = (float*)(ws + P1_OFF);
    float* pcnt  = (float*)(ws + PC_OFF);

    const int tid  = threadIdx.x;
    const int lane = tid & 63;
    const int wv   = tid >> 6;        // wave 0..3
    const int quad = lane >> 4;       // 0..3
    const int ncol = lane & 15;
    const int rowbase = blockIdx.x * 128;
    const int kcbase  = blockIdx.y * KCHUNK;

    // two A-side row tiles per wave
    const int m0 = rowbase + wv * 32 + ncol;
    const int m1 = m0 + 16;
    const float prx0 = posT[m0], pry0 = posT[N + m0], prz0 = posT[2 * N + m0];
    const float thr0 = 6.25f - posT[3 * N + m0];
    const float prx1 = posT[m1], pry1 = posT[N + m1], prz1 = posT[2 * N + m1];
    const float thr1 = 6.25f - posT[3 * N + m1];

    short8 bones;
    #pragma unroll
    for (int j = 0; j < 8; ++j) bones[j] = (ncol == 0) ? (short)0x3F80 : (short)0;

    floatx4 acc[2][2], accc[2];
    #pragma unroll
    for (int t = 0; t < 2; ++t) {
        acc[t][0] = (floatx4){0.f,0.f,0.f,0.f};
        acc[t][1] = (floatx4){0.f,0.f,0.f,0.f};
        accc[t]   = (floatx4){0.f,0.f,0.f,0.f};
    }

    const int c32 = tid & 31, r8 = tid >> 5;
    for (int kb = 0; kb < KCHUNK; kb += BK) {
        const int kg = kcbase + kb;
        __syncthreads();
        #pragma unroll
        for (int rr = 0; rr < 4; ++rr) {
            const int r = r8 + rr * 8;
            *(uint4*)&sY[r * YSTR + c32 * 8] = *(const uint4*)(y1t + (size_t)r * N + kg + c32 * 8);
        }
        {   // stage pos rows x,y,z,r2: 4 x 256 floats, 1 float4/thread
            const int dim = tid >> 6, i = tid & 63;
            *(float4*)&sPos[dim * PSTR + i * 4] = *(const float4*)(posT + (size_t)dim * N + kg + i * 4);
        }
        __syncthreads();

        #pragma unroll 2
        for (int kt = 0; kt < BK; kt += 32) {
            const int koff = kt + quad * 8;
            const float4 xa = *(const float4*)&sPos[koff],            xb = *(const float4*)&sPos[koff + 4];
            const float4 ya = *(const float4*)&sPos[PSTR + koff],     yb = *(const float4*)&sPos[PSTR + koff + 4];
            const float4 za = *(const float4*)&sPos[2 * PSTR + koff], zb = *(const float4*)&sPos[2 * PSTR + koff + 4];
            const float4 ra = *(const float4*)&sPos[3 * PSTR + koff], rb = *(const float4*)&sPos[3 * PSTR + koff + 4];

            short8 af0, af1;
            MKA8(af0, xa, xb, ya, yb, za, zb, ra, rb, prx0, pry0, prz0, thr0)
            MKA8(af1, xa, xb, ya, yb, za, zb, ra, rb, prx1, pry1, prz1, thr1)

            const short8 b0 = *(const short8*)&sY[(ncol)      * YSTR + koff];
            const short8 b1 = *(const short8*)&sY[(16 + ncol) * YSTR + koff];

            acc[0][0] = __builtin_amdgcn_mfma_f32_16x16x32_bf16(af0, b0, acc[0][0], 0, 0, 0);
            acc[0][1] = __builtin_amdgcn_mfma_f32_16x16x32_bf16(af0, b1, acc[0][1], 0, 0, 0);
            accc[0]   = __builtin_amdgcn_mfma_f32_16x16x32_bf16(af0, bones, accc[0], 0, 0, 0);
            acc[1][0] = __builtin_amdgcn_mfma_f32_16x16x32_bf16(af1, b0, acc[1][0], 0, 0, 0);
            acc[1][1] = __builtin_amdgcn_mfma_f32_16x16x32_bf16(af1, b1, acc[1][1], 0, 0, 0);
            accc[1]   = __builtin_amdgcn_mfma_f32_16x16x32_bf16(af1, bones, accc[1], 0, 0, 0);
        }
    }

    // C layout: col = ncol, row = quad*4 + r
    float* p1 = part1 + (size_t)blockIdx.y * N * 32;
    float* pc = pcnt  + (size_t)blockIdx.y * N;
    #pragma unroll
    for (int t = 0; t < 2; ++t) {
        const int orow0 = rowbase + wv * 32 + t * 16 + quad * 4;
        #pragma unroll
        for (int r = 0; r < 4; ++r) {
            const int orow = orow0 + r;
            p1[(size_t)orow * 32 + ncol]      = acc[t][0][r];
            p1[(size_t)orow * 32 + 16 + ncol] = acc[t][1][r];
            if (ncol == 0) pc[orow] = accc[t][r];
        }
    }
}

// ---------------- mlp2: h = relu(sum/(cnt+eps)); y2 = h@W2+b2 -> y2T bf16 [8][N]; cntT ----------------
__global__ __launch_bounds__(256) void k_mlp2(
    const float* __restrict__ W2,    // (32,8)
    const float* __restrict__ b2,    // (8,)
    char* __restrict__ ws)
{
    __shared__ float sW2[256], sb2[8];
    __shared__ __hip_bfloat16 sT[8 * YSTR];
    const int tid = threadIdx.x;
    for (int i = tid; i < 256; i += THREADS) sW2[i] = W2[i];
    if (tid < 8) sb2[tid] = b2[tid];
    __syncthreads();

    const int row = blockIdx.x * THREADS + tid;
    const float* part1 = (const float*)(ws + P1_OFF);
    const float* pcnt  = (const float*)(ws + PC_OFF);

    float s[32];
    #pragma unroll
    for (int c = 0; c < 32; ++c) s[c] = 0.0f;
    float cv = 0.0f;
    for (int kc = 0; kc < KCHUNKS; ++kc) {
        const float4* p4 = (const float4*)(part1 + ((size_t)kc * N + row) * 32);
        #pragma unroll
        for (int k = 0; k < 8; ++k) {
            const float4 v = p4[k];
            s[4*k+0] += v.x; s[4*k+1] += v.y; s[4*k+2] += v.z; s[4*k+3] += v.w;
        }
        cv += pcnt[(size_t)kc * N + row];
    }
    const float inv = 1.0f / (cv + 1e-6f);
    ((float*)(ws + CNTT_OFF))[row] = cv;

    float o[8];
    #pragma unroll
    for (int j = 0; j < 8; ++j) o[j] = sb2[j];
    #pragma unroll
    for (int c = 0; c < 32; ++c) {
        const float hv = fmaxf(s[c] * inv, 0.0f);
        #pragma unroll
        for (int j = 0; j < 8; ++j) o[j] += hv * sW2[c * 8 + j];
    }
    #pragma unroll
    for (int j = 0; j < 8; ++j)
        sT[j * YSTR + tid] = __float2bfloat16(o[j]);
    __syncthreads();
    __hip_bfloat16* y2t = (__hip_bfloat16*)(ws + Y2T_OFF);
    const int kb = blockIdx.x * THREADS;
    const int c32 = tid & 31, r8 = tid >> 5;
    *(uint4*)(y2t + (size_t)r8 * N + kb + c32 * 8) = *(const uint4*)&sT[r8 * YSTR + c32 * 8];
}

// ---------------- agg2: partial sums(A @ y2) via MFMA, 128-row blocks ----------------
__global__ __launch_bounds__(256) void k_agg2(char* __restrict__ ws)
{
    __shared__ __hip_bfloat16 sY[9 * YSTR];   // rows 0-7 data, row 8 zeros
    __shared__ float sPos[4 * PSTR];

    const float* posT = (const float*)(ws + POST_OFF);
    const __hip_bfloat16* y2t = (const __hip_bfloat16*)(ws + Y2T_OFF);
    float* part2 = (float*)(ws + P2_OFF);

    const int tid  = threadIdx.x;
    const int lane = tid & 63;
    const int wv   = tid >> 6;
    const int quad = lane >> 4;
    const int ncol = lane & 15;
    const int rowbase = blockIdx.x * 128;
    const int kcbase  = blockIdx.y * KCHUNK;

    // zero row 8 (read by lanes with ncol >= 8)
    if (tid < 32) {
        const uint4 z = {0u, 0u, 0u, 0u};
        *(uint4*)&sY[8 * YSTR + tid * 8] = z;
    }

    const int m0 = rowbase + wv * 32 + ncol;
    const int m1 = m0 + 16;
    const float prx0 = posT[m0], pry0 = posT[N + m0], prz0 = posT[2 * N + m0];
    const float thr0 = 6.25f - posT[3 * N + m0];
    const float prx1 = posT[m1], pry1 = posT[N + m1], prz1 = posT[2 * N + m1];
    const float thr1 = 6.25f - posT[3 * N + m1];

    const int brow = (ncol < 8) ? ncol : 8;

    floatx4 acc[2];
    acc[0] = (floatx4){0.f,0.f,0.f,0.f};
    acc[1] = (floatx4){0.f,0.f,0.f,0.f};

    const int c32 = tid & 31, r8 = tid >> 5;
    for (int kb = 0; kb < KCHUNK; kb += BK) {
        const int kg = kcbase + kb;
        __syncthreads();
        *(uint4*)&sY[r8 * YSTR + c32 * 8] = *(const uint4*)(y2t + (size_t)r8 * N + kg + c32 * 8);
        {
            const int dim = tid >> 6, i = tid & 63;
            *(float4*)&sPos[dim * PSTR + i * 4] = *(const float4*)(posT + (size_t)dim * N + kg + i * 4);
        }
        __syncthreads();

        #pragma unroll 2
        for (int kt = 0; kt < BK; kt += 32) {
            const int koff = kt + quad * 8;
            const float4 xa = *(const float4*)&sPos[koff],            xb = *(const float4*)&sPos[koff + 4];
            const float4 ya = *(const float4*)&sPos[PSTR + koff],     yb = *(const float4*)&sPos[PSTR + koff + 4];
            const float4 za = *(const float4*)&sPos[2 * PSTR + koff], zb = *(const float4*)&sPos[2 * PSTR + koff + 4];
            const float4 ra = *(const float4*)&sPos[3 * PSTR + koff], rb = *(const float4*)&sPos[3 * PSTR + koff + 4];

            short8 af0, af1;
            MKA8(af0, xa, xb, ya, yb, za, zb, ra, rb, prx0, pry0, prz0, thr0)
            MKA8(af1, xa, xb, ya, yb, za, zb, ra, rb, prx1, pry1, prz1, thr1)

            const short8 b0 = *(const short8*)&sY[brow * YSTR + koff];
            acc[0] = __builtin_amdgcn_mfma_f32_16x16x32_bf16(af0, b0, acc[0], 0, 0, 0);
            acc[1] = __builtin_amdgcn_mfma_f32_16x16x32_bf16(af1, b0, acc[1], 0, 0, 0);
        }
    }

    float* p2 = part2 + (size_t)blockIdx.y * N * 8;
    #pragma unroll
    for (int t = 0; t < 2; ++t) {
        const int orow0 = rowbase + wv * 32 + t * 16 + quad * 4;
        #pragma unroll
        for (int r = 0; r < 4; ++r) {
            if (ncol < 8) {
                const int orow = orow0 + r;
                p2[(size_t)orow * 8 + ncol] = acc[t][r];
            }
        }
    }
}

// ---------------- out = relu(sum/(cnt+eps)) -> float32 ----------------
__global__ __launch_bounds__(256) void k_out(char* __restrict__ ws, float* __restrict__ out)
{
    const int tid = threadIdx.x;
    const int row = blockIdx.x * THREADS + tid;
    const float* part2 = (const float*)(ws + P2_OFF);
    const float  cv  = ((const float*)(ws + CNTT_OFF))[row];
    const float  inv = 1.0f / (cv + 1e-6f);
    float s[8];
    #pragma unroll
    for (int c = 0; c < 8; ++c) s[c] = 0.0f;
    for (int kc = 0; kc < KCHUNKS; ++kc) {
        const float4* p4 = (const float4*)(part2 + ((size_t)kc * N + row) * 8);
        const float4 v0 = p4[0], v1 = p4[1];
        s[0] += v0.x; s[1] += v0.y; s[2] += v0.z; s[3] += v0.w;
        s[4] += v1.x; s[5] += v1.y; s[6] += v1.z; s[7] += v1.w;
    }
    float4* op = (float4*)(out + (size_t)row * 8);
    op[0] = make_float4(fmaxf(s[0] * inv, 0.0f), fmaxf(s[1] * inv, 0.0f),
                        fmaxf(s[2] * inv, 0.0f), fmaxf(s[3] * inv, 0.0f));
    op[1] = make_float4(fmaxf(s[4] * inv, 0.0f), fmaxf(s[5] * inv, 0.0f),
                        fmaxf(s[6] * inv, 0.0f), fmaxf(s[7] * inv, 0.0f));
}

extern "C" void kernel_launch(void* const* d_in, const int* in_sizes, int n_in,
                              void* d_out, int out_size, void* d_ws, size_t ws_size,
                              hipStream_t stream) {
    (void)in_sizes; (void)n_in; (void)out_size; (void)ws_size;
    char* ws = (char*)d_ws;
    const float* lpf = (const float*)d_in[0];
    const float* B   = (const float*)d_in[1];
    const float* emb = (const float*)d_in[2];
    const float* W1  = (const float*)d_in[3];
    const float* b1  = (const float*)d_in[4];
    const float* W2  = (const float*)d_in[5];
    const float* b2  = (const float*)d_in[6];

    k_prep<<<N / 32, THREADS, 0, stream>>>(lpf, B, emb, W1, b1, ws);
    k_agg1<<<dim3(N / 128, KCHUNKS), THREADS, 0, stream>>>(ws);
    k_mlp2<<<N / THREADS, THREADS, 0, stream>>>(W2, b2, ws);
    k_agg2<<<dim3(N / 128, KCHUNKS), THREADS, 0, stream>>>(ws);
    k_out <<<N / THREADS, THREADS, 0, stream>>>(ws, (float*)d_out);
}

// Round 17
// 121.176 us; speedup vs baseline: 1.9171x; 1.0013x over previous
//
#include <hip/hip_runtime.h>
#include <hip/hip_bf16.h>

#define N 8192
#define THREADS 256
#define KCHUNKS 8
#define KCHUNK (N / KCHUNKS)   // 1024
#define BK 256
#define YSTR 264               // padded LDS stride (bf16 elements)
#define PSTR 264               // padded LDS stride (floats) for pos rows

typedef __attribute__((ext_vector_type(8))) short short8;
typedef __attribute__((ext_vector_type(4))) float floatx4;

// ---- workspace byte offsets (total ~11.6 MB) ----
#define POST_OFF  0u           // float[4*N]: x,y,z,r2 rows     131072
#define Y1T_OFF   131072u      // bf16[32*N]                    524288
#define Y2T_OFF   655360u      // bf16[8*N]                     131072
#define P1_OFF    786432u      // float[8*N*32]                8388608
#define PC_OFF    9175040u     // float[8*N]                    262144
#define P2_OFF    9437184u     // float[8*N*8]                 2097152
#define CNTT_OFF  11534336u    // float[N]                       32768

__device__ __forceinline__ float bf2f(__hip_bfloat16 x) { return __bfloat162float(x); }

// ---------------- prep v2: 256 blocks x 32 rows, 8 threads/row ----------------
__global__ __launch_bounds__(256) void k_prep(
    const float* __restrict__ lpf,    // (N,4) float32
    const float* __restrict__ Bm,     // (3,16)
    const float* __restrict__ emb,    // (13,8)
    const float* __restrict__ W1,     // (40,32)
    const float* __restrict__ b1,     // (32,)
    char* __restrict__ ws)
{
    __shared__ float sB[48], sEmb[104], sW1[1280], sb1[32];
    __shared__ float xfs[32][41];              // per-row feature vector
    __shared__ __hip_bfloat16 sT[32 * 36];     // [feat][row_local], stride 36

    const int tid = threadIdx.x;
    for (int i = tid; i < 48;   i += THREADS) sB[i]   = Bm[i];
    for (int i = tid; i < 104;  i += THREADS) sEmb[i] = emb[i];
    for (int i = tid; i < 1280; i += THREADS) sW1[i]  = W1[i];
    for (int i = tid; i < 32;   i += THREADS) sb1[i]  = b1[i];
    __syncthreads();

    const int row_local = tid >> 3;            // 0..31
    const int fslice    = tid & 7;             // 0..7
    const int base = blockIdx.x * 32;
    const int row  = base + row_local;

    const float4 lp = ((const float4*)lpf)[row];
    const float px = lp.x, py = lp.y, pz = lp.z;
    int fi = (int)lp.w;
    fi = fi < 0 ? 0 : (fi > 12 ? 12 : fi);
    const float r2 = px * px + py * py + pz * pz;
    float* posT = (float*)(ws + POST_OFF);
    if (fslice < 4) {
        const float v = (fslice == 0) ? px : (fslice == 1) ? py : (fslice == 2) ? pz : r2;
        posT[(size_t)fslice * N + row] = v;
    }

    const float TWO_PI = 6.283185307179586f;
    #pragma unroll
    for (int t = 0; t < 2; ++t) {
        const int k = fslice * 2 + t;          // 0..15
        const float pr = (px * sB[k] + py * sB[16 + k] + pz * sB[32 + k]) * TWO_PI;
        xfs[row_local][k]      = sinf(pr);
        xfs[row_local][16 + k] = cosf(pr);
    }
    xfs[row_local][32 + fslice] = sEmb[fi * 8 + fslice];
    __syncthreads();

    float acc[4];
    #pragma unroll
    for (int j = 0; j < 4; ++j) acc[j] = sb1[fslice * 4 + j];
    #pragma unroll
    for (int f = 0; f < 40; ++f) {
        const float xv = xfs[row_local][f];
        #pragma unroll
        for (int j = 0; j < 4; ++j)
            acc[j] += xv * sW1[f * 32 + fslice * 4 + j];
    }
    #pragma unroll
    for (int j = 0; j < 4; ++j)
        sT[(fslice * 4 + j) * 36 + row_local] = __float2bfloat16(acc[j]);
    __syncthreads();

    __hip_bfloat16* y1t = (__hip_bfloat16*)(ws + Y1T_OFF);
    if (tid < 128) {
        const int feat = tid >> 2, chunk = tid & 3;
        *(uint4*)(y1t + (size_t)feat * N + base + chunk * 8) = *(const uint4*)&sT[feat * 36 + chunk * 8];
    }
}

// mask from r2-form: s = r_k^2 - 2*dot(p_m,p_k);  s < 6.25 - r_m^2  <=>  d^2 < 6.25
#define MKA(PX,PY,PZ,RR,DST,IDX,PRX,PRY,PRZ,THR) { \
    const float dot = fmaf((PZ), (PRZ), fmaf((PY), (PRY), (PX) * (PRX))); \
    const float sv  = fmaf(dot, -2.0f, (RR)); \
    DST[IDX] = (sv < (THR)) ? (short)0x3F80 : (short)0; }

#define MKA8(AF, XA,XB,YA,YB,ZA,ZB,RA,RB, PRX,PRY,PRZ,THR) \
    MKA(XA.x, YA.x, ZA.x, RA.x, AF, 0, PRX, PRY, PRZ, THR) \
    MKA(XA.y, YA.y, ZA.y, RA.y, AF, 1, PRX, PRY, PRZ, THR) \
    MKA(XA.z, YA.z, ZA.z, RA.z, AF, 2, PRX, PRY, PRZ, THR) \
    MKA(XA.w, YA.w, ZA.w, RA.w, AF, 3, PRX, PRY, PRZ, THR) \
    MKA(XB.x, YB.x, ZB.x, RB.x, AF, 4, PRX, PRY, PRZ, THR) \
    MKA(XB.y, YB.y, ZB.y, RB.y, AF, 5, PRX, PRY, PRZ, THR) \
    MKA(XB.z, YB.z, ZB.z, RB.z, AF, 6, PRX, PRY, PRZ, THR) \
    MKA(XB.w, YB.w, ZB.w, RB.w, AF, 7, PRX, PRY, PRZ, THR)

// ---------------- agg1: partial sums(A @ y1) + cnt via MFMA, 128-row blocks ----------------
__global__ __launch_bounds__(256, 2) void k_agg1(char* __restrict__ ws)
{
    __shared__ __hip_bfloat16 sY[32 * YSTR];
    __shared__ float sPos[4 * PSTR];

    const float* posT = (const float*)(ws + POST_OFF);
    const __hip_bfloat16* y1t = (const __hip_bfloat16*)(ws + Y1T_OFF);
    float* part1 = (float*)(ws + P1_OFF);
    float* pcnt  = (float*)(ws + PC_OFF);

    const int tid  = threadIdx.x;
    const int lane = tid & 63;
    const int wv   = tid >> 6;        // wave 0..3
    const int quad = lane >> 4;       // 0..3
    const int ncol = lane & 15;
    const int rowbase = blockIdx.x * 128;
    const int kcbase  = blockIdx.y * KCHUNK;

    const int m0 = rowbase + wv * 32 + ncol;
    const int m1 = m0 + 16;
    const float prx0 = posT[m0], pry0 = posT[N + m0], prz0 = posT[2 * N + m0];
    const float thr0 = 6.25f - posT[3 * N + m0];
    const float prx1 = posT[m1], pry1 = posT[N + m1], prz1 = posT[2 * N + m1];
    const float thr1 = 6.25f - posT[3 * N + m1];

    short8 bones;
    #pragma unroll
    for (int j = 0; j < 8; ++j) bones[j] = (ncol == 0) ? (short)0x3F80 : (short)0;

    floatx4 acc[2][2], accc[2];
    #pragma unroll
    for (int t = 0; t < 2; ++t) {
        acc[t][0] = (floatx4){0.f,0.f,0.f,0.f};
        acc[t][1] = (floatx4){0.f,0.f,0.f,0.f};
        accc[t]   = (floatx4){0.f,0.f,0.f,0.f};
    }

    const int c32 = tid & 31, r8 = tid >> 5;
    for (int kb = 0; kb < KCHUNK; kb += BK) {
        const int kg = kcbase + kb;
        __syncthreads();
        #pragma unroll
        for (int rr = 0; rr < 4; ++rr) {
            const int r = r8 + rr * 8;
            *(uint4*)&sY[r * YSTR + c32 * 8] = *(const uint4*)(y1t + (size_t)r * N + kg + c32 * 8);
        }
        {   // stage pos rows x,y,z,r2: 4 x 256 floats, 1 float4/thread
            const int dim = tid >> 6, i = tid & 63;
            *(float4*)&sPos[dim * PSTR + i * 4] = *(const float4*)(posT + (size_t)dim * N + kg + i * 4);
        }
        __syncthreads();

        #pragma unroll 4
        for (int kt = 0; kt < BK; kt += 32) {
            const int koff = kt + quad * 8;
            const float4 xa = *(const float4*)&sPos[koff],            xb = *(const float4*)&sPos[koff + 4];
            const float4 ya = *(const float4*)&sPos[PSTR + koff],     yb = *(const float4*)&sPos[PSTR + koff + 4];
            const float4 za = *(const float4*)&sPos[2 * PSTR + koff], zb = *(const float4*)&sPos[2 * PSTR + koff + 4];
            const float4 ra = *(const float4*)&sPos[3 * PSTR + koff], rb = *(const float4*)&sPos[3 * PSTR + koff + 4];

            short8 af0, af1;
            MKA8(af0, xa, xb, ya, yb, za, zb, ra, rb, prx0, pry0, prz0, thr0)
            MKA8(af1, xa, xb, ya, yb, za, zb, ra, rb, prx1, pry1, prz1, thr1)

            const short8 b0 = *(const short8*)&sY[(ncol)      * YSTR + koff];
            const short8 b1 = *(const short8*)&sY[(16 + ncol) * YSTR + koff];

            acc[0][0] = __builtin_amdgcn_mfma_f32_16x16x32_bf16(af0, b0, acc[0][0], 0, 0, 0);
            acc[0][1] = __builtin_amdgcn_mfma_f32_16x16x32_bf16(af0, b1, acc[0][1], 0, 0, 0);
            accc[0]   = __builtin_amdgcn_mfma_f32_16x16x32_bf16(af0, bones, accc[0], 0, 0, 0);
            acc[1][0] = __builtin_amdgcn_mfma_f32_16x16x32_bf16(af1, b0, acc[1][0], 0, 0, 0);
            acc[1][1] = __builtin_amdgcn_mfma_f32_16x16x32_bf16(af1, b1, acc[1][1], 0, 0, 0);
            accc[1]   = __builtin_amdgcn_mfma_f32_16x16x32_bf16(af1, bones, accc[1], 0, 0, 0);
        }
    }

    // C layout: col = ncol, row = quad*4 + r
    float* p1 = part1 + (size_t)blockIdx.y * N * 32;
    float* pc = pcnt  + (size_t)blockIdx.y * N;
    #pragma unroll
    for (int t = 0; t < 2; ++t) {
        const int orow0 = rowbase + wv * 32 + t * 16 + quad * 4;
        #pragma unroll
        for (int r = 0; r < 4; ++r) {
            const int orow = orow0 + r;
            p1[(size_t)orow * 32 + ncol]      = acc[t][0][r];
            p1[(size_t)orow * 32 + 16 + ncol] = acc[t][1][r];
            if (ncol == 0) pc[orow] = accc[t][r];
        }
    }
}

// ---------------- mlp2: h = relu(sum/(cnt+eps)); y2 = h@W2+b2 -> y2T bf16 [8][N]; cntT ----------------
__global__ __launch_bounds__(256) void k_mlp2(
    const float* __restrict__ W2,    // (32,8)
    const float* __restrict__ b2,    // (8,)
    char* __restrict__ ws)
{
    __shared__ float sW2[256], sb2[8];
    __shared__ __hip_bfloat16 sT[8 * YSTR];
    const int tid = threadIdx.x;
    for (int i = tid; i < 256; i += THREADS) sW2[i] = W2[i];
    if (tid < 8) sb2[tid] = b2[tid];
    __syncthreads();

    const int row = blockIdx.x * THREADS + tid;
    const float* part1 = (const float*)(ws + P1_OFF);
    const float* pcnt  = (const float*)(ws + PC_OFF);

    float s[32];
    #pragma unroll
    for (int c = 0; c < 32; ++c) s[c] = 0.0f;
    float cv = 0.0f;
    for (int kc = 0; kc < KCHUNKS; ++kc) {
        const float4* p4 = (const float4*)(part1 + ((size_t)kc * N + row) * 32);
        #pragma unroll
        for (int k = 0; k < 8; ++k) {
            const float4 v = p4[k];
            s[4*k+0] += v.x; s[4*k+1] += v.y; s[4*k+2] += v.z; s[4*k+3] += v.w;
        }
        cv += pcnt[(size_t)kc * N + row];
    }
    const float inv = 1.0f / (cv + 1e-6f);
    ((float*)(ws + CNTT_OFF))[row] = cv;

    float o[8];
    #pragma unroll
    for (int j = 0; j < 8; ++j) o[j] = sb2[j];
    #pragma unroll
    for (int c = 0; c < 32; ++c) {
        const float hv = fmaxf(s[c] * inv, 0.0f);
        #pragma unroll
        for (int j = 0; j < 8; ++j) o[j] += hv * sW2[c * 8 + j];
    }
    #pragma unroll
    for (int j = 0; j < 8; ++j)
        sT[j * YSTR + tid] = __float2bfloat16(o[j]);
    __syncthreads();
    __hip_bfloat16* y2t = (__hip_bfloat16*)(ws + Y2T_OFF);
    const int kb = blockIdx.x * THREADS;
    const int c32 = tid & 31, r8 = tid >> 5;
    *(uint4*)(y2t + (size_t)r8 * N + kb + c32 * 8) = *(const uint4*)&sT[r8 * YSTR + c32 * 8];
}

// ---------------- agg2: partial sums(A @ y2) via MFMA, 128-row blocks ----------------
__global__ __launch_bounds__(256, 2) void k_agg2(char* __restrict__ ws)
{
    __shared__ __hip_bfloat16 sY[9 * YSTR];   // rows 0-7 data, row 8 zeros
    __shared__ float sPos[4 * PSTR];

    const float* posT = (const float*)(ws + POST_OFF);
    const __hip_bfloat16* y2t = (const __hip_bfloat16*)(ws + Y2T_OFF);
    float* part2 = (float*)(ws + P2_OFF);

    const int tid  = threadIdx.x;
    const int lane = tid & 63;
    const int wv   = tid >> 6;
    const int quad = lane >> 4;
    const int ncol = lane & 15;
    const int rowbase = blockIdx.x * 128;
    const int kcbase  = blockIdx.y * KCHUNK;

    // zero row 8 (read by lanes with ncol >= 8)
    if (tid < 32) {
        const uint4 z = {0u, 0u, 0u, 0u};
        *(uint4*)&sY[8 * YSTR + tid * 8] = z;
    }

    const int m0 = rowbase + wv * 32 + ncol;
    const int m1 = m0 + 16;
    const float prx0 = posT[m0], pry0 = posT[N + m0], prz0 = posT[2 * N + m0];
    const float thr0 = 6.25f - posT[3 * N + m0];
    const float prx1 = posT[m1], pry1 = posT[N + m1], prz1 = posT[2 * N + m1];
    const float thr1 = 6.25f - posT[3 * N + m1];

    const int brow = (ncol < 8) ? ncol : 8;

    floatx4 acc[2];
    acc[0] = (floatx4){0.f,0.f,0.f,0.f};
    acc[1] = (floatx4){0.f,0.f,0.f,0.f};

    const int c32 = tid & 31, r8 = tid >> 5;
    for (int kb = 0; kb < KCHUNK; kb += BK) {
        const int kg = kcbase + kb;
        __syncthreads();
        *(uint4*)&sY[r8 * YSTR + c32 * 8] = *(const uint4*)(y2t + (size_t)r8 * N + kg + c32 * 8);
        {
            const int dim = tid >> 6, i = tid & 63;
            *(float4*)&sPos[dim * PSTR + i * 4] = *(const float4*)(posT + (size_t)dim * N + kg + i * 4);
        }
        __syncthreads();

        #pragma unroll 4
        for (int kt = 0; kt < BK; kt += 32) {
            const int koff = kt + quad * 8;
            const float4 xa = *(const float4*)&sPos[koff],            xb = *(const float4*)&sPos[koff + 4];
            const float4 ya = *(const float4*)&sPos[PSTR + koff],     yb = *(const float4*)&sPos[PSTR + koff + 4];
            const float4 za = *(const float4*)&sPos[2 * PSTR + koff], zb = *(const float4*)&sPos[2 * PSTR + koff + 4];
            const float4 ra = *(const float4*)&sPos[3 * PSTR + koff], rb = *(const float4*)&sPos[3 * PSTR + koff + 4];

            short8 af0, af1;
            MKA8(af0, xa, xb, ya, yb, za, zb, ra, rb, prx0, pry0, prz0, thr0)
            MKA8(af1, xa, xb, ya, yb, za, zb, ra, rb, prx1, pry1, prz1, thr1)

            const short8 b0 = *(const short8*)&sY[brow * YSTR + koff];
            acc[0] = __builtin_amdgcn_mfma_f32_16x16x32_bf16(af0, b0, acc[0], 0, 0, 0);
            acc[1] = __builtin_amdgcn_mfma_f32_16x16x32_bf16(af1, b0, acc[1], 0, 0, 0);
        }
    }

    float* p2 = part2 + (size_t)blockIdx.y * N * 8;
    #pragma unroll
    for (int t = 0; t < 2; ++t) {
        const int orow0 = rowbase + wv * 32 + t * 16 + quad * 4;
        #pragma unroll
        for (int r = 0; r < 4; ++r) {
            if (ncol < 8) {
                const int orow = orow0 + r;
                p2[(size_t)orow * 8 + ncol] = acc[t][r];
            }
        }
    }
}

// ---------------- out = relu(sum/(cnt+eps)) -> float32 ----------------
__global__ __launch_bounds__(256) void k_out(char* __restrict__ ws, float* __restrict__ out)
{
    const int tid = threadIdx.x;
    const int row = blockIdx.x * THREADS + tid;
    const float* part2 = (const float*)(ws + P2_OFF);
    const float  cv  = ((const float*)(ws + CNTT_OFF))[row];
    const float  inv = 1.0f / (cv + 1e-6f);
    float s[8];
    #pragma unroll
    for (int c = 0; c < 8; ++c) s[c] = 0.0f;
    for (int kc = 0; kc < KCHUNKS; ++kc) {
        const float4* p4 = (const float4*)(part2 + ((size_t)kc * N + row) * 8);
        const float4 v0 = p4[0], v1 = p4[1];
        s[0] += v0.x; s[1] += v0.y; s[2] += v0.z; s[3] += v0.w;
        s[4] += v1.x; s[5] += v1.y; s[6] += v1.z; s[7] += v1.w;
    }
    float4* op = (float4*)(out + (size_t)row * 8);
    op[0] = make_float4(fmaxf(s[0] * inv, 0.0f), fmaxf(s[1] * inv, 0.0f),
                        fmaxf(s[2] * inv, 0.0f), fmaxf(s[3] * inv, 0.0f));
    op[1] = make_float4(fmaxf(s[4] * inv, 0.0f), fmaxf(s[5] * inv, 0.0f),
                        fmaxf(s[6] * inv, 0.0f), fmaxf(s[7] * inv, 0.0f));
}

extern "C" void kernel_launch(void* const* d_in, const int* in_sizes, int n_in,
                              void* d_out, int out_size, void* d_ws, size_t ws_size,
                              hipStream_t stream) {
    (void)in_sizes; (void)n_in; (void)out_size; (void)ws_size;
    char* ws = (char*)d_ws;
    const float* lpf = (const float*)d_in[0];
    const float* B   = (const float*)d_in[1];
    const float* emb = (const float*)d_in[2];
    const float* W1  = (const float*)d_in[3];
    const float* b1  = (const float*)d_in[4];
    const float* W2  = (const float*)d_in[5];
    const float* b2  = (const float*)d_in[6];

    k_prep<<<N / 32, THREADS, 0, stream>>>(lpf, B, emb, W1, b1, ws);
    k_agg1<<<dim3(N / 128, KCHUNKS), THREADS, 0, stream>>>(ws);
    k_mlp2<<<N / THREADS, THREADS, 0, stream>>>(W2, b2, ws);
    k_agg2<<<dim3(N / 128, KCHUNKS), THREADS, 0, stream>>>(ws);
    k_out <<<N / THREADS, THREADS, 0, stream>>>(ws, (float*)d_out);
}

// Round 18
// 120.724 us; speedup vs baseline: 1.9243x; 1.0037x over previous
//
#include <hip/hip_runtime.h>
#include <hip/hip_bf16.h>

#define N 8192
#define THREADS 256
#define KCHUNKS 8
#define KCHUNK (N / KCHUNKS)   // 1024
#define BK 512
#define YSTR 520               // padded LDS stride (bf16 elements)
#define PSTR 520               // padded LDS stride (floats) for pos rows

typedef __attribute__((ext_vector_type(8))) short short8;
typedef __attribute__((ext_vector_type(4))) float floatx4;

// ---- workspace byte offsets (total ~11.6 MB) ----
#define POST_OFF  0u           // float[4*N]: x,y,z,r2 rows     131072
#define Y1T_OFF   131072u      // bf16[32*N]                    524288
#define Y2T_OFF   655360u      // bf16[8*N]                     131072
#define P1_OFF    786432u      // float[8*N*32]                8388608
#define PC_OFF    9175040u     // float[8*N]                    262144
#define P2_OFF    9437184u     // float[8*N*8]                 2097152
#define CNTT_OFF  11534336u    // float[N]                       32768

__device__ __forceinline__ float bf2f(__hip_bfloat16 x) { return __bfloat162float(x); }

// ---------------- prep v2: 256 blocks x 32 rows, 8 threads/row ----------------
__global__ __launch_bounds__(256) void k_prep(
    const float* __restrict__ lpf,    // (N,4) float32
    const float* __restrict__ Bm,     // (3,16)
    const float* __restrict__ emb,    // (13,8)
    const float* __restrict__ W1,     // (40,32)
    const float* __restrict__ b1,     // (32,)
    char* __restrict__ ws)
{
    __shared__ float sB[48], sEmb[104], sW1[1280], sb1[32];
    __shared__ float xfs[32][41];              // per-row feature vector
    __shared__ __hip_bfloat16 sT[32 * 36];     // [feat][row_local], stride 36

    const int tid = threadIdx.x;
    for (int i = tid; i < 48;   i += THREADS) sB[i]   = Bm[i];
    for (int i = tid; i < 104;  i += THREADS) sEmb[i] = emb[i];
    for (int i = tid; i < 1280; i += THREADS) sW1[i]  = W1[i];
    for (int i = tid; i < 32;   i += THREADS) sb1[i]  = b1[i];
    __syncthreads();

    const int row_local = tid >> 3;            // 0..31
    const int fslice    = tid & 7;             // 0..7
    const int base = blockIdx.x * 32;
    const int row  = base + row_local;

    const float4 lp = ((const float4*)lpf)[row];
    const float px = lp.x, py = lp.y, pz = lp.z;
    int fi = (int)lp.w;
    fi = fi < 0 ? 0 : (fi > 12 ? 12 : fi);
    const float r2 = px * px + py * py + pz * pz;
    float* posT = (float*)(ws + POST_OFF);
    if (fslice < 4) {
        const float v = (fslice == 0) ? px : (fslice == 1) ? py : (fslice == 2) ? pz : r2;
        posT[(size_t)fslice * N + row] = v;
    }

    const float TWO_PI = 6.283185307179586f;
    #pragma unroll
    for (int t = 0; t < 2; ++t) {
        const int k = fslice * 2 + t;          // 0..15
        const float pr = (px * sB[k] + py * sB[16 + k] + pz * sB[32 + k]) * TWO_PI;
        xfs[row_local][k]      = sinf(pr);
        xfs[row_local][16 + k] = cosf(pr);
    }
    xfs[row_local][32 + fslice] = sEmb[fi * 8 + fslice];
    __syncthreads();

    float acc[4];
    #pragma unroll
    for (int j = 0; j < 4; ++j) acc[j] = sb1[fslice * 4 + j];
    #pragma unroll
    for (int f = 0; f < 40; ++f) {
        const float xv = xfs[row_local][f];
        #pragma unroll
        for (int j = 0; j < 4; ++j)
            acc[j] += xv * sW1[f * 32 + fslice * 4 + j];
    }
    #pragma unroll
    for (int j = 0; j < 4; ++j)
        sT[(fslice * 4 + j) * 36 + row_local] = __float2bfloat16(acc[j]);
    __syncthreads();

    __hip_bfloat16* y1t = (__hip_bfloat16*)(ws + Y1T_OFF);
    if (tid < 128) {
        const int feat = tid >> 2, chunk = tid & 3;
        *(uint4*)(y1t + (size_t)feat * N + base + chunk * 8) = *(const uint4*)&sT[feat * 36 + chunk * 8];
    }
}

// mask from r2-form: s = r_k^2 - 2*dot(p_m,p_k);  s < 6.25 - r_m^2  <=>  d^2 < 6.25
#define MKA(PX,PY,PZ,RR,DST,IDX,PRX,PRY,PRZ,THR) { \
    const float dot = fmaf((PZ), (PRZ), fmaf((PY), (PRY), (PX) * (PRX))); \
    const float sv  = fmaf(dot, -2.0f, (RR)); \
    DST[IDX] = (sv < (THR)) ? (short)0x3F80 : (short)0; }

#define MKA8(AF, XA,XB,YA,YB,ZA,ZB,RA,RB, PRX,PRY,PRZ,THR) \
    MKA(XA.x, YA.x, ZA.x, RA.x, AF, 0, PRX, PRY, PRZ, THR) \
    MKA(XA.y, YA.y, ZA.y, RA.y, AF, 1, PRX, PRY, PRZ, THR) \
    MKA(XA.z, YA.z, ZA.z, RA.z, AF, 2, PRX, PRY, PRZ, THR) \
    MKA(XA.w, YA.w, ZA.w, RA.w, AF, 3, PRX, PRY, PRZ, THR) \
    MKA(XB.x, YB.x, ZB.x, RB.x, AF, 4, PRX, PRY, PRZ, THR) \
    MKA(XB.y, YB.y, ZB.y, RB.y, AF, 5, PRX, PRY, PRZ, THR) \
    MKA(XB.z, YB.z, ZB.z, RB.z, AF, 6, PRX, PRY, PRZ, THR) \
    MKA(XB.w, YB.w, ZB.w, RB.w, AF, 7, PRX, PRY, PRZ, THR)

// ---------------- agg1: partial sums(A @ y1) + cnt via MFMA, 128-row blocks, BK=512 ----------------
__global__ __launch_bounds__(256, 2) void k_agg1(char* __restrict__ ws)
{
    __shared__ __hip_bfloat16 sY[32 * YSTR];   // 33280 B
    __shared__ float sPos[4 * PSTR];           //  8320 B

    const float* posT = (const float*)(ws + POST_OFF);
    const __hip_bfloat16* y1t = (const __hip_bfloat16*)(ws + Y1T_OFF);
    float* part1 = (float*)(ws + P1_OFF);
    float* pcnt  = (float*)(ws + PC_OFF);

    const int tid  = threadIdx.x;
    const int lane = tid & 63;
    const int wv   = tid >> 6;        // wave 0..3
    const int quad = lane >> 4;       // 0..3
    const int ncol = lane & 15;
    const int rowbase = blockIdx.x * 128;
    const int kcbase  = blockIdx.y * KCHUNK;

    const int m0 = rowbase + wv * 32 + ncol;
    const int m1 = m0 + 16;
    const float prx0 = posT[m0], pry0 = posT[N + m0], prz0 = posT[2 * N + m0];
    const float thr0 = 6.25f - posT[3 * N + m0];
    const float prx1 = posT[m1], pry1 = posT[N + m1], prz1 = posT[2 * N + m1];
    const float thr1 = 6.25f - posT[3 * N + m1];

    short8 bones;
    #pragma unroll
    for (int j = 0; j < 8; ++j) bones[j] = (ncol == 0) ? (short)0x3F80 : (short)0;

    floatx4 acc[2][2], accc[2];
    #pragma unroll
    for (int t = 0; t < 2; ++t) {
        acc[t][0] = (floatx4){0.f,0.f,0.f,0.f};
        acc[t][1] = (floatx4){0.f,0.f,0.f,0.f};
        accc[t]   = (floatx4){0.f,0.f,0.f,0.f};
    }

    const int c32 = tid & 31, r8 = tid >> 5;
    for (int kb = 0; kb < KCHUNK; kb += BK) {
        const int kg = kcbase + kb;
        __syncthreads();
        #pragma unroll
        for (int rr = 0; rr < 4; ++rr) {
            const int r = r8 + rr * 8;
            #pragma unroll
            for (int cc = 0; cc < 2; ++cc)
                *(uint4*)&sY[r * YSTR + cc * 256 + c32 * 8] =
                    *(const uint4*)(y1t + (size_t)r * N + kg + cc * 256 + c32 * 8);
        }
        {   // stage pos rows x,y,z,r2: 4 x 512 floats
            const int dim = tid >> 6, i = tid & 63;
            #pragma unroll
            for (int cc = 0; cc < 2; ++cc)
                *(float4*)&sPos[dim * PSTR + cc * 256 + i * 4] =
                    *(const float4*)(posT + (size_t)dim * N + kg + cc * 256 + i * 4);
        }
        __syncthreads();

        #pragma unroll 4
        for (int kt = 0; kt < BK; kt += 32) {
            const int koff = kt + quad * 8;
            const float4 xa = *(const float4*)&sPos[koff],            xb = *(const float4*)&sPos[koff + 4];
            const float4 ya = *(const float4*)&sPos[PSTR + koff],     yb = *(const float4*)&sPos[PSTR + koff + 4];
            const float4 za = *(const float4*)&sPos[2 * PSTR + koff], zb = *(const float4*)&sPos[2 * PSTR + koff + 4];
            const float4 ra = *(const float4*)&sPos[3 * PSTR + koff], rb = *(const float4*)&sPos[3 * PSTR + koff + 4];

            short8 af0, af1;
            MKA8(af0, xa, xb, ya, yb, za, zb, ra, rb, prx0, pry0, prz0, thr0)
            MKA8(af1, xa, xb, ya, yb, za, zb, ra, rb, prx1, pry1, prz1, thr1)

            const short8 b0 = *(const short8*)&sY[(ncol)      * YSTR + koff];
            const short8 b1 = *(const short8*)&sY[(16 + ncol) * YSTR + koff];

            acc[0][0] = __builtin_amdgcn_mfma_f32_16x16x32_bf16(af0, b0, acc[0][0], 0, 0, 0);
            acc[0][1] = __builtin_amdgcn_mfma_f32_16x16x32_bf16(af0, b1, acc[0][1], 0, 0, 0);
            accc[0]   = __builtin_amdgcn_mfma_f32_16x16x32_bf16(af0, bones, accc[0], 0, 0, 0);
            acc[1][0] = __builtin_amdgcn_mfma_f32_16x16x32_bf16(af1, b0, acc[1][0], 0, 0, 0);
            acc[1][1] = __builtin_amdgcn_mfma_f32_16x16x32_bf16(af1, b1, acc[1][1], 0, 0, 0);
            accc[1]   = __builtin_amdgcn_mfma_f32_16x16x32_bf16(af1, bones, accc[1], 0, 0, 0);
        }
    }

    // C layout: col = ncol, row = quad*4 + r
    float* p1 = part1 + (size_t)blockIdx.y * N * 32;
    float* pc = pcnt  + (size_t)blockIdx.y * N;
    #pragma unroll
    for (int t = 0; t < 2; ++t) {
        const int orow0 = rowbase + wv * 32 + t * 16 + quad * 4;
        #pragma unroll
        for (int r = 0; r < 4; ++r) {
            const int orow = orow0 + r;
            p1[(size_t)orow * 32 + ncol]      = acc[t][0][r];
            p1[(size_t)orow * 32 + 16 + ncol] = acc[t][1][r];
            if (ncol == 0) pc[orow] = accc[t][r];
        }
    }
}

// ---------------- mlp2: h = relu(sum/(cnt+eps)); y2 = h@W2+b2 -> y2T bf16 [8][N]; cntT ----------------
__global__ __launch_bounds__(256) void k_mlp2(
    const float* __restrict__ W2,    // (32,8)
    const float* __restrict__ b2,    // (8,)
    char* __restrict__ ws)
{
    __shared__ float sW2[256], sb2[8];
    __shared__ __hip_bfloat16 sT[8 * 264];
    const int tid = threadIdx.x;
    for (int i = tid; i < 256; i += THREADS) sW2[i] = W2[i];
    if (tid < 8) sb2[tid] = b2[tid];
    __syncthreads();

    const int row = blockIdx.x * THREADS + tid;
    const float* part1 = (const float*)(ws + P1_OFF);
    const float* pcnt  = (const float*)(ws + PC_OFF);

    float s[32];
    #pragma unroll
    for (int c = 0; c < 32; ++c) s[c] = 0.0f;
    float cv = 0.0f;
    for (int kc = 0; kc < KCHUNKS; ++kc) {
        const float4* p4 = (const float4*)(part1 + ((size_t)kc * N + row) * 32);
        #pragma unroll
        for (int k = 0; k < 8; ++k) {
            const float4 v = p4[k];
            s[4*k+0] += v.x; s[4*k+1] += v.y; s[4*k+2] += v.z; s[4*k+3] += v.w;
        }
        cv += pcnt[(size_t)kc * N + row];
    }
    const float inv = 1.0f / (cv + 1e-6f);
    ((float*)(ws + CNTT_OFF))[row] = cv;

    float o[8];
    #pragma unroll
    for (int j = 0; j < 8; ++j) o[j] = sb2[j];
    #pragma unroll
    for (int c = 0; c < 32; ++c) {
        const float hv = fmaxf(s[c] * inv, 0.0f);
        #pragma unroll
        for (int j = 0; j < 8; ++j) o[j] += hv * sW2[c * 8 + j];
    }
    #pragma unroll
    for (int j = 0; j < 8; ++j)
        sT[j * 264 + tid] = __float2bfloat16(o[j]);
    __syncthreads();
    __hip_bfloat16* y2t = (__hip_bfloat16*)(ws + Y2T_OFF);
    const int kb = blockIdx.x * THREADS;
    const int c32 = tid & 31, r8 = tid >> 5;
    *(uint4*)(y2t + (size_t)r8 * N + kb + c32 * 8) = *(const uint4*)&sT[r8 * 264 + c32 * 8];
}

// ---------------- agg2: partial sums(A @ y2) via MFMA, 128-row blocks, BK=512 ----------------
__global__ __launch_bounds__(256, 2) void k_agg2(char* __restrict__ ws)
{
    __shared__ __hip_bfloat16 sY[9 * YSTR];   // rows 0-7 data, row 8 zeros
    __shared__ float sPos[4 * PSTR];

    const float* posT = (const float*)(ws + POST_OFF);
    const __hip_bfloat16* y2t = (const __hip_bfloat16*)(ws + Y2T_OFF);
    float* part2 = (float*)(ws + P2_OFF);

    const int tid  = threadIdx.x;
    const int lane = tid & 63;
    const int wv   = tid >> 6;
    const int quad = lane >> 4;
    const int ncol = lane & 15;
    const int rowbase = blockIdx.x * 128;
    const int kcbase  = blockIdx.y * KCHUNK;

    // zero row 8 (read by lanes with ncol >= 8)
    for (int i = tid; i < 64; i += THREADS) {
        const uint4 z = {0u, 0u, 0u, 0u};
        *(uint4*)&sY[8 * YSTR + i * 8] = z;
    }

    const int m0 = rowbase + wv * 32 + ncol;
    const int m1 = m0 + 16;
    const float prx0 = posT[m0], pry0 = posT[N + m0], prz0 = posT[2 * N + m0];
    const float thr0 = 6.25f - posT[3 * N + m0];
    const float prx1 = posT[m1], pry1 = posT[N + m1], prz1 = posT[2 * N + m1];
    const float thr1 = 6.25f - posT[3 * N + m1];

    const int brow = (ncol < 8) ? ncol : 8;

    floatx4 acc[2];
    acc[0] = (floatx4){0.f,0.f,0.f,0.f};
    acc[1] = (floatx4){0.f,0.f,0.f,0.f};

    const int c32 = tid & 31, r8 = tid >> 5;
    for (int kb = 0; kb < KCHUNK; kb += BK) {
        const int kg = kcbase + kb;
        __syncthreads();
        #pragma unroll
        for (int cc = 0; cc < 2; ++cc)
            *(uint4*)&sY[r8 * YSTR + cc * 256 + c32 * 8] =
                *(const uint4*)(y2t + (size_t)r8 * N + kg + cc * 256 + c32 * 8);
        {
            const int dim = tid >> 6, i = tid & 63;
            #pragma unroll
            for (int cc = 0; cc < 2; ++cc)
                *(float4*)&sPos[dim * PSTR + cc * 256 + i * 4] =
                    *(const float4*)(posT + (size_t)dim * N + kg + cc * 256 + i * 4);
        }
        __syncthreads();

        #pragma unroll 4
        for (int kt = 0; kt < BK; kt += 32) {
            const int koff = kt + quad * 8;
            const float4 xa = *(const float4*)&sPos[koff],            xb = *(const float4*)&sPos[koff + 4];
            const float4 ya = *(const float4*)&sPos[PSTR + koff],     yb = *(const float4*)&sPos[PSTR + koff + 4];
            const float4 za = *(const float4*)&sPos[2 * PSTR + koff], zb = *(const float4*)&sPos[2 * PSTR + koff + 4];
            const float4 ra = *(const float4*)&sPos[3 * PSTR + koff], rb = *(const float4*)&sPos[3 * PSTR + koff + 4];

            short8 af0, af1;
            MKA8(af0, xa, xb, ya, yb, za, zb, ra, rb, prx0, pry0, prz0, thr0)
            MKA8(af1, xa, xb, ya, yb, za, zb, ra, rb, prx1, pry1, prz1, thr1)

            const short8 b0 = *(const short8*)&sY[brow * YSTR + koff];
            acc[0] = __builtin_amdgcn_mfma_f32_16x16x32_bf16(af0, b0, acc[0], 0, 0, 0);
            acc[1] = __builtin_amdgcn_mfma_f32_16x16x32_bf16(af1, b0, acc[1], 0, 0, 0);
        }
    }

    float* p2 = part2 + (size_t)blockIdx.y * N * 8;
    #pragma unroll
    for (int t = 0; t < 2; ++t) {
        const int orow0 = rowbase + wv * 32 + t * 16 + quad * 4;
        #pragma unroll
        for (int r = 0; r < 4; ++r) {
            if (ncol < 8) {
                const int orow = orow0 + r;
                p2[(size_t)orow * 8 + ncol] = acc[t][r];
            }
        }
    }
}

// ---------------- out = relu(sum/(cnt+eps)) -> float32 ----------------
__global__ __launch_bounds__(256) void k_out(char* __restrict__ ws, float* __restrict__ out)
{
    const int tid = threadIdx.x;
    const int row = blockIdx.x * THREADS + tid;
    const float* part2 = (const float*)(ws + P2_OFF);
    const float  cv  = ((const float*)(ws + CNTT_OFF))[row];
    const float  inv = 1.0f / (cv + 1e-6f);
    float s[8];
    #pragma unroll
    for (int c = 0; c < 8; ++c) s[c] = 0.0f;
    for (int kc = 0; kc < KCHUNKS; ++kc) {
        const float4* p4 = (const float4*)(part2 + ((size_t)kc * N + row) * 8);
        const float4 v0 = p4[0], v1 = p4[1];
        s[0] += v0.x; s[1] += v0.y; s[2] += v0.z; s[3] += v0.w;
        s[4] += v1.x; s[5] += v1.y; s[6] += v1.z; s[7] += v1.w;
    }
    float4* op = (float4*)(out + (size_t)row * 8);
    op[0] = make_float4(fmaxf(s[0] * inv, 0.0f), fmaxf(s[1] * inv, 0.0f),
                        fmaxf(s[2] * inv, 0.0f), fmaxf(s[3] * inv, 0.0f));
    op[1] = make_float4(fmaxf(s[4] * inv, 0.0f), fmaxf(s[5] * inv, 0.0f),
                        fmaxf(s[6] * inv, 0.0f), fmaxf(s[7] * inv, 0.0f));
}

extern "C" void kernel_launch(void* const* d_in, const int* in_sizes, int n_in,
                              void* d_out, int out_size, void* d_ws, size_t ws_size,
                              hipStream_t stream) {
    (void)in_sizes; (void)n_in; (void)out_size; (void)ws_size;
    char* ws = (char*)d_ws;
    const float* lpf = (const float*)d_in[0];
    const float* B   = (const float*)d_in[1];
    const float* emb = (const float*)d_in[2];
    const float* W1  = (const float*)d_in[3];
    const float* b1  = (const float*)d_in[4];
    const float* W2  = (const float*)d_in[5];
    const float* b2  = (const float*)d_in[6];

    k_prep<<<N / 32, THREADS, 0, stream>>>(lpf, B, emb, W1, b1, ws);
    k_agg1<<<dim3(N / 128, KCHUNKS), THREADS, 0, stream>>>(ws);
    k_mlp2<<<N / THREADS, THREADS, 0, stream>>>(W2, b2, ws);
    k_agg2<<<dim3(N / 128, KCHUNKS), THREADS, 0, stream>>>(ws);
    k_out <<<N / THREADS, THREADS, 0, stream>>>(ws, (float*)d_out);
}